// Round 1
// baseline (7318.171 us; speedup 1.0000x reference)
//
#include <hip/hip_runtime.h>
#include <math.h>

#define BSZ   512
#define TSTEPS 16
#define HID   2048
#define G4    8192
#define ZD    512
#define ABF   16384
#define LOG2PI_F 1.8378770664093453f

typedef float  f32x4  __attribute__((ext_vector_type(4)));
typedef __bf16 bf16x8 __attribute__((ext_vector_type(8)));
typedef unsigned short u16;
typedef u16 u16x4 __attribute__((ext_vector_type(4)));

__device__ __forceinline__ u16 f2bf(float f){
  union { float f; unsigned u; } v; v.f = f;
  unsigned u = v.u;
  return (u16)((u + 0x7FFFu + ((u >> 16) & 1u)) >> 16);   // RNE
}
__device__ __forceinline__ float bf2f(u16 u){
  union { unsigned u; float f; } v; v.u = ((unsigned)u) << 16; return v.f;
}
__device__ __forceinline__ float sigm(float x){ return 1.f/(1.f + expf(-x)); }

__device__ __forceinline__ void load_lds16(const void* g, void* l){
  __builtin_amdgcn_global_load_lds(
      (const __attribute__((address_space(1))) void*)g,
      (__attribute__((address_space(3))) void*)l, 16, 0, 0);
}

__device__ __forceinline__ float wsum(float v){
  #pragma unroll
  for (int o = 32; o; o >>= 1) v += __shfl_down(v, o, 64);
  return v;
}

// ---------------- utility kernels ----------------
__global__ __launch_bounds__(256) void zero_kernel(float* __restrict__ p, int n4){
  int i = blockIdx.x*256 + threadIdx.x;
  const int st = gridDim.x*256;
  f32x4 z = {0.f,0.f,0.f,0.f};
  for (; i < n4; i += st) ((f32x4*)p)[i] = z;
}

__global__ __launch_bounds__(256) void cvt_kernel(const float* __restrict__ s, u16* __restrict__ d, int n4){
  int i = blockIdx.x*256 + threadIdx.x;
  const int st = gridDim.x*256;
  for (; i < n4; i += st){
    f32x4 v = ((const f32x4*)s)[i];
    u16x4 o;
    o[0]=f2bf(v[0]); o[1]=f2bf(v[1]); o[2]=f2bf(v[2]); o[3]=f2bf(v[3]);
    ((u16x4*)d)[i] = o;
  }
}

// ---------------- attention params -> Fx,Fy,gamma ----------------
__global__ __launch_bounds__(256) void attn_kernel(
    const u16* __restrict__ h_dec_bf, const float* __restrict__ attnW,
    const float* __restrict__ attn_b,
    float* __restrict__ Fx, float* __restrict__ Fy, float* __restrict__ gamma)
{
  const int b = blockIdx.x;
  const int tid = threadIdx.x;
  __shared__ float red[5][256];
  {
    float a0=0,a1=0,a2=0,a3=0,a4=0;
    const u16* h = h_dec_bf + (size_t)b*HID;
    for (int k = tid; k < HID; k += 256){
      const float hv = bf2f(h[k]);
      a0 += hv*attnW[k];
      a1 += hv*attnW[HID + k];
      a2 += hv*attnW[2*HID + k];
      a3 += hv*attnW[3*HID + k];
      a4 += hv*attnW[4*HID + k];
    }
    red[0][tid]=a0; red[1][tid]=a1; red[2][tid]=a2; red[3][tid]=a3; red[4][tid]=a4;
  }
  __syncthreads();
  for (int s = 128; s > 0; s >>= 1){
    if (tid < s){
      #pragma unroll
      for (int j = 0; j < 5; j++) red[j][tid] += red[j][tid + s];
    }
    __syncthreads();
  }
  __shared__ float prm[5];
  if (tid < 5){
    const float p = red[tid][0] + attn_b[tid];
    float v;
    if (tid <= 1)      v = 64.5f*(p + 1.f);          // gx, gy
    else if (tid == 3) v = (127.f/31.f)*expf(p);     // delta
    else               v = expf(p);                  // sigma2, gamma
    prm[tid] = v;
  }
  __syncthreads();
  const float gx = prm[0], gy = prm[1], s2 = prm[2], dl = prm[3], gm = prm[4];
  const float i2s = 1.f/(2.f*s2);
  __shared__ __align__(16) float sFx[4096], sFy[4096];
  for (int i = tid; i < 4096; i += 256){
    const int n = i >> 7, a = i & 127;
    const float rn = (float)n - 16.5f;
    const float tx = ((float)a - (gx + rn*dl))*i2s;
    const float ty = ((float)a - (gy + rn*dl))*i2s;
    sFx[i] = expf(-tx*tx);
    sFy[i] = expf(-ty*ty);
  }
  __syncthreads();
  __shared__ float inv[64];
  if (tid < 64){
    const int n = tid & 31;
    const float* src = (tid < 32) ? &sFx[n*128] : &sFy[n*128];
    float s = 0.f;
    for (int a = 0; a < 128; a++) s += src[a];
    inv[tid] = 1.f/(s + 1e-9f);
  }
  __syncthreads();
  for (int i = tid; i < 4096; i += 256){
    const int n = i >> 7;
    Fx[(size_t)b*4096 + i] = sFx[i]*inv[n];
    Fy[(size_t)b*4096 + i] = sFy[i]*inv[32 + n];
  }
  if (tid == 0) gamma[b] = gm;
}

// ---------------- x_hat = x - sigmoid(canvas) ----------------
__global__ __launch_bounds__(256) void xhat_kernel(
    const float* __restrict__ x, const float* __restrict__ canvas, float* __restrict__ xh)
{
  int i = blockIdx.x*256 + threadIdx.x;
  const int st = gridDim.x*256;
  const int n4 = (ABF/4)*BSZ;
  for (; i < n4; i += st){
    f32x4 xv = ((const f32x4*)x)[i];
    f32x4 cv = ((const f32x4*)canvas)[i];
    f32x4 o;
    #pragma unroll
    for (int k = 0; k < 4; k++) o[k] = xv[k] - sigm(cv[k]);
    ((f32x4*)xh)[i] = o;
  }
}

// ---------------- glimpse read: r = [Fy@x@Fx^T, Fy@xhat@Fx^T]*gamma ----------------
__global__ __launch_bounds__(256) void read_kernel(
    const float* __restrict__ x, const float* __restrict__ xhat,
    const float* __restrict__ Fx, const float* __restrict__ Fy,
    const float* __restrict__ gamma, u16* __restrict__ r_bf)
{
  const int b = blockIdx.x;
  const int tid = threadIdx.x;
  __shared__ __align__(16) float sAux[32*132];      // Fx, later Fy (padded rows)
  __shared__ __align__(16) float sT[2][128*33];     // T[B][m] per mat
  for (int i = tid; i < 4096; i += 256)
    sAux[(i >> 7)*132 + (i & 127)] = Fx[(size_t)b*4096 + i];
  __syncthreads();
  const int Bg = tid & 31;
  const int mg = tid >> 5;
  #pragma unroll
  for (int mat = 0; mat < 2; mat++){
    const float* img = ((mat == 0) ? x : xhat) + (size_t)b*ABF;
    float acc[4][4] = {};
    for (int a = 0; a < 128; a += 4){
      f32x4 im[4], fx4[4];
      #pragma unroll
      for (int i = 0; i < 4; i++) im[i]  = *(const f32x4*)&img[(Bg + 32*i)*128 + a];
      #pragma unroll
      for (int j = 0; j < 4; j++) fx4[j] = *(const f32x4*)&sAux[(mg*4 + j)*132 + a];
      #pragma unroll
      for (int i = 0; i < 4; i++)
        #pragma unroll
        for (int j = 0; j < 4; j++)
          acc[i][j] += im[i][0]*fx4[j][0] + im[i][1]*fx4[j][1]
                     + im[i][2]*fx4[j][2] + im[i][3]*fx4[j][3];
    }
    #pragma unroll
    for (int i = 0; i < 4; i++)
      #pragma unroll
      for (int j = 0; j < 4; j++)
        sT[mat][(Bg + 32*i)*33 + mg*4 + j] = acc[i][j];
  }
  __syncthreads();
  for (int i = tid; i < 4096; i += 256)
    sAux[(i >> 7)*132 + (i & 127)] = Fy[(size_t)b*4096 + i];
  __syncthreads();
  const int mat = tid >> 7;
  const int rem = tid & 127;
  const int ng  = rem >> 4;
  const int mg2 = rem & 15;
  float acc[4][2] = {};
  for (int B4 = 0; B4 < 128; B4 += 4){
    f32x4 fy4[4];
    #pragma unroll
    for (int i = 0; i < 4; i++) fy4[i] = *(const f32x4*)&sAux[(ng*4 + i)*132 + B4];
    #pragma unroll
    for (int k = 0; k < 4; k++){
      const float t0 = sT[mat][(B4 + k)*33 + mg2*2 + 0];
      const float t1 = sT[mat][(B4 + k)*33 + mg2*2 + 1];
      #pragma unroll
      for (int i = 0; i < 4; i++){
        acc[i][0] += fy4[i][k]*t0;
        acc[i][1] += fy4[i][k]*t1;
      }
    }
  }
  const float gam = gamma[b];
  #pragma unroll
  for (int i = 0; i < 4; i++)
    #pragma unroll
    for (int j = 0; j < 2; j++)
      r_bf[(size_t)b*2048 + mat*1024 + (ng*4 + i)*32 + mg2*2 + j] = f2bf(acc[i][j]*gam);
}

// ---------------- bf16 B^T GEMM: C = sum_p Ap @ Wp^T (+bias), MFMA 16x16x32 ----------------
template<int BM, int BN>
__global__ __launch_bounds__(256) void gemm_bt(
    const u16* __restrict__ A0, int lda0, const u16* __restrict__ W0p, int ldw0, int K0,
    const u16* __restrict__ A1, int lda1, const u16* __restrict__ W1p, int ldw1, int K1,
    const u16* __restrict__ A2, int lda2, const u16* __restrict__ W2p, int ldw2, int K2,
    const float* __restrict__ bias0, const float* __restrict__ bias_hi,
    const u16* __restrict__ W_hi, int nsplit,
    float* __restrict__ C, int ldc)
{
  constexpr int BK = 64;
  constexpr int FI = BM/32;
  constexpr int FJ = BN/32;
  __shared__ __align__(16) u16 Asm[BM*BK];
  __shared__ __align__(16) u16 Bsm[BN*BK];
  const int tid  = threadIdx.x;
  const int wave = tid >> 6;
  const int lane = tid & 63;
  const int wm = wave & 1, wn = wave >> 1;
  const int m0 = blockIdx.y * BM;
  const int n0 = blockIdx.x * BN;
  const float* bias = bias0;
  const u16* W0 = W0p;
  if (nsplit > 0 && n0 >= nsplit){
    W0 = W_hi - (size_t)nsplit * ldw0;
    bias = bias_hi - nsplit;
  }
  f32x4 acc[FI][FJ];
  #pragma unroll
  for (int i = 0; i < FI; i++)
    #pragma unroll
    for (int j = 0; j < FJ; j++) acc[i][j] = (f32x4){0.f,0.f,0.f,0.f};

  const int lr = lane & 15;
  const int lq = lane >> 4;

  const u16* pA[3]  = {A0, A1, A2};
  const u16* pW[3]  = {W0, W1p, W2p};
  const int  ldA[3] = {lda0, lda1, lda2};
  const int  ldW[3] = {ldw0, ldw1, ldw2};
  const int  Ks[3]  = {K0, K1, K2};

  for (int p = 0; p < 3; p++){
    const int Kp = Ks[p];
    if (Kp == 0) continue;
    const u16* Ap = pA[p];
    const u16* Wp = pW[p];
    const int lda = ldA[p];
    const int ldw = ldW[p];
    for (int kt = 0; kt < Kp; kt += BK){
      __syncthreads();
      // stage A (swizzled so frag b128 reads are 2-way max)
      constexpr int NCA = BM*BK/8;
      #pragma unroll
      for (int it = 0; it < NCA/256; it++){
        const int cb = it*256 + wave*64;
        const int c  = cb + lane;
        const int row = c >> 3;
        const int c8  = (c & 7) ^ (row & 7);
        load_lds16(Ap + (size_t)(m0 + row)*lda + kt + c8*8, &Asm[cb*8]);
      }
      constexpr int NCB = BN*BK/8;
      #pragma unroll
      for (int it = 0; it < NCB/256; it++){
        const int cb = it*256 + wave*64;
        const int c  = cb + lane;
        const int row = c >> 3;
        const int c8  = (c & 7) ^ (row & 7);
        load_lds16(Wp + (size_t)(n0 + row)*ldw + kt + c8*8, &Bsm[cb*8]);
      }
      __syncthreads();
      #pragma unroll
      for (int ks = 0; ks < 2; ks++){
        bf16x8 af[FI], bfr[FJ];
        #pragma unroll
        for (int i = 0; i < FI; i++){
          const int row = wm*(BM/2) + i*16 + lr;
          const int xx = (ks*4 + lq) ^ (row & 7);
          af[i] = *(const bf16x8*)&Asm[row*BK + xx*8];
        }
        #pragma unroll
        for (int j = 0; j < FJ; j++){
          const int row = wn*(BN/2) + j*16 + lr;
          const int xx = (ks*4 + lq) ^ (row & 7);
          bfr[j] = *(const bf16x8*)&Bsm[row*BK + xx*8];
        }
        #pragma unroll
        for (int i = 0; i < FI; i++)
          #pragma unroll
          for (int j = 0; j < FJ; j++)
            acc[i][j] = __builtin_amdgcn_mfma_f32_16x16x32_bf16(af[i], bfr[j], acc[i][j], 0, 0, 0);
      }
    }
  }
  // epilogue: C/D layout col=lane&15, row=(lane>>4)*4+reg  (m89-verified)
  #pragma unroll
  for (int i = 0; i < FI; i++){
    const int gm = m0 + wm*(BM/2) + i*16 + lq*4;
    #pragma unroll
    for (int j = 0; j < FJ; j++){
      const int gn = n0 + wn*(BN/2) + j*16 + lr;
      const float bv = bias ? bias[gn] : 0.f;
      #pragma unroll
      for (int r = 0; r < 4; r++)
        C[(size_t)(gm + r)*ldc + gn] = acc[i][j][r] + bv;
    }
  }
}

// ---------------- LSTM pointwise ----------------
__global__ __launch_bounds__(256) void lstm_kernel(
    const float* __restrict__ g, float* __restrict__ c, float* __restrict__ h)
{
  const int idx = blockIdx.x*256 + threadIdx.x;  // < 262144 (1M/4)
  const int m = idx >> 9;
  const int q = idx & 511;
  const size_t gb = (size_t)m*G4 + q*4;
  f32x4 gi = *(const f32x4*)&g[gb];
  f32x4 gf = *(const f32x4*)&g[gb + HID];
  f32x4 gg = *(const f32x4*)&g[gb + 2*HID];
  f32x4 go = *(const f32x4*)&g[gb + 3*HID];
  const size_t cb = (size_t)m*HID + q*4;
  f32x4 cv = *(const f32x4*)&c[cb];
  f32x4 cn, hn;
  #pragma unroll
  for (int k = 0; k < 4; k++){
    const float ck = sigm(gf[k])*cv[k] + sigm(gi[k])*tanhf(gg[k]);
    cn[k] = ck;
    hn[k] = sigm(go[k])*tanhf(ck);
  }
  *(f32x4*)&c[cb] = cn;
  *(f32x4*)&h[cb] = hn;
}

// ---------------- MDL renorm (3 kernels over 1M elements) ----------------
__global__ __launch_bounds__(256) void mdl_reduce1(const float* __restrict__ h, float* __restrict__ s){
  float s1 = 0.f, s2 = 0.f;
  int i = blockIdx.x*256 + threadIdx.x;
  const int st = 256*256;
  for (; i < (1<<18); i += st){
    f32x4 v = ((const f32x4*)h)[i];
    s1 += v[0]+v[1]+v[2]+v[3];
    s2 += v[0]*v[0]+v[1]*v[1]+v[2]*v[2]+v[3]*v[3];
  }
  s1 = wsum(s1); s2 = wsum(s2);
  __shared__ float a1[4], a2[4];
  const int w = threadIdx.x >> 6;
  if ((threadIdx.x & 63) == 0){ a1[w] = s1; a2[w] = s2; }
  __syncthreads();
  if (threadIdx.x == 0){
    atomicAdd(&s[0], a1[0]+a1[1]+a1[2]+a1[3]);
    atomicAdd(&s[1], a2[0]+a2[1]+a2[2]+a2[3]);
  }
}

__global__ __launch_bounds__(256) void mdl_reduce2(const float* __restrict__ h, float* __restrict__ s){
  const float mean = s[0] * (1.f/1048576.f);
  const float var  = (s[1] - 1048576.f*mean*mean) * (1.f/1048575.f);
  const float istd = 1.f/sqrtf(var);
  float se = 0.f;
  int i = blockIdx.x*256 + threadIdx.x;
  const int st = 256*256;
  for (; i < (1<<18); i += st){
    f32x4 v = ((const f32x4*)h)[i];
    #pragma unroll
    for (int k = 0; k < 4; k++){
      const float u = (v[k] - mean)*istd;
      se += expf(-0.5f*u*u);
    }
  }
  se = wsum(se);
  __shared__ float a1[4];
  const int w = threadIdx.x >> 6;
  if ((threadIdx.x & 63) == 0) a1[w] = se;
  __syncthreads();
  if (threadIdx.x == 0) atomicAdd(&s[2], a1[0]+a1[1]+a1[2]+a1[3]);
}

__global__ __launch_bounds__(256) void mdl_scale(
    const float* __restrict__ h, const float* __restrict__ s, u16* __restrict__ hb)
{
  const float mean = s[0]*(1.f/1048576.f);
  const float var  = (s[1] - 1048576.f*mean*mean)*(1.f/1048575.f);
  const float stdv = sqrtf(var);
  // lse = log(sum exp(-u^2/2)) - log(std) - 0.5*log(2pi); safe: all exp terms <= 1
  const float lse = logf(s[2]) - logf(stdv) - 0.5f*LOG2PI_F;
  const float l = fmaxf(-lse, 0.f) + log1pf(expf(-fabsf(lse)));   // logaddexp(0,lse)-lse
  const int i = blockIdx.x*256 + threadIdx.x;   // < 262144
  f32x4 v = ((const f32x4*)h)[i];
  u16x4 o;
  #pragma unroll
  for (int k = 0; k < 4; k++) o[k] = f2bf(v[k]*l);
  ((u16x4*)hb)[i] = o;
}

// ---------------- z = mu + exp(logsig)*eps ----------------
__global__ __launch_bounds__(256) void z_kernel(
    const float* __restrict__ zb, const float* __restrict__ ep, u16* __restrict__ zo)
{
  const int idx = blockIdx.x*256 + threadIdx.x;  // < 65536
  const int m = idx >> 7;
  const int q = idx & 127;
  f32x4 mu = *(const f32x4*)&zb[(size_t)m*1024 + q*4];
  f32x4 ls = *(const f32x4*)&zb[(size_t)m*1024 + 512 + q*4];
  f32x4 ev = *(const f32x4*)&ep[(size_t)m*512 + q*4];
  u16x4 o;
  #pragma unroll
  for (int k = 0; k < 4; k++) o[k] = f2bf(mu[k] + expf(ls[k])*ev[k]);
  ((u16x4*)zo)[idx] = o;
}

// ---------------- write: canvas += (Fy^T @ w @ Fx)/gamma ----------------
__global__ __launch_bounds__(256) void write_kernel(
    const float* __restrict__ wb, const float* __restrict__ Fx,
    const float* __restrict__ Fy, const float* __restrict__ gamma,
    float* __restrict__ canvas)
{
  const int b = blockIdx.x;
  const int tid = threadIdx.x;
  __shared__ float sW[1024];                       // w[n][m]
  __shared__ __align__(16) float sFy[4096];        // Fy[n][B]
  __shared__ float sU[128*33];                     // U[B][m]
  __shared__ __align__(16) float sFx[32*132];      // Fx[m][a] padded
  for (int i = tid; i < 1024; i += 256) sW[i] = wb[(size_t)b*1024 + i];
  for (int i = tid; i < 4096; i += 256){
    sFy[i] = Fy[(size_t)b*4096 + i];
    sFx[(i >> 7)*132 + (i & 127)] = Fx[(size_t)b*4096 + i];
  }
  __syncthreads();
  {
    const int Bg = tid & 31, mg = tid >> 5;
    float acc[4][4] = {};
    for (int n = 0; n < 32; n++){
      float fy[4], wv[4];
      #pragma unroll
      for (int i = 0; i < 4; i++) fy[i] = sFy[n*128 + Bg + 32*i];
      #pragma unroll
      for (int j = 0; j < 4; j++) wv[j] = sW[n*32 + mg*4 + j];
      #pragma unroll
      for (int i = 0; i < 4; i++)
        #pragma unroll
        for (int j = 0; j < 4; j++) acc[i][j] += fy[i]*wv[j];
    }
    #pragma unroll
    for (int i = 0; i < 4; i++)
      #pragma unroll
      for (int j = 0; j < 4; j++)
        sU[(Bg + 32*i)*33 + mg*4 + j] = acc[i][j];
  }
  __syncthreads();
  {
    const int Bg = tid & 31, ag = tid >> 5;
    float acc[64];
    #pragma unroll
    for (int k = 0; k < 64; k++) acc[k] = 0.f;
    for (int mm = 0; mm < 32; mm++){
      float u[4];
      #pragma unroll
      for (int i = 0; i < 4; i++) u[i] = sU[(Bg + 32*i)*33 + mm];
      f32x4 fx[4];
      #pragma unroll
      for (int k = 0; k < 4; k++) fx[k] = *(const f32x4*)&sFx[mm*132 + ag*16 + k*4];
      #pragma unroll
      for (int i = 0; i < 4; i++)
        #pragma unroll
        for (int k = 0; k < 4; k++)
          #pragma unroll
          for (int cc = 0; cc < 4; cc++)
            acc[i*16 + k*4 + cc] += u[i]*fx[k][cc];
    }
    const float ig = 1.f/gamma[b];
    #pragma unroll
    for (int i = 0; i < 4; i++){
      const int B_ = Bg + 32*i;
      #pragma unroll
      for (int k = 0; k < 4; k++){
        float* cp = &canvas[(size_t)b*ABF + B_*128 + ag*16 + k*4];
        f32x4 cv = *(const f32x4*)cp;
        #pragma unroll
        for (int cc = 0; cc < 4; cc++) cv[cc] += acc[i*16 + k*4 + cc]*ig;
        *(f32x4*)cp = cv;
      }
    }
  }
}

// ---------------- host ----------------
extern "C" void kernel_launch(void* const* d_in, const int* in_sizes, int n_in,
                              void* d_out, int out_size, void* d_ws, size_t ws_size,
                              hipStream_t stream)
{
  (void)in_sizes; (void)n_in; (void)out_size; (void)ws_size;
  const float* x      = (const float*)d_in[0];
  const float* eps    = (const float*)d_in[1];
  const float* encWih = (const float*)d_in[2];
  const float* encWhh = (const float*)d_in[3];
  const float* enc_b  = (const float*)d_in[4];
  const float* decWih = (const float*)d_in[5];
  const float* decWhh = (const float*)d_in[6];
  const float* dec_b  = (const float*)d_in[7];
  const float* muW    = (const float*)d_in[8];
  const float* mu_b   = (const float*)d_in[9];
  const float* sigW   = (const float*)d_in[10];
  const float* sig_b  = (const float*)d_in[11];
  const float* attnW  = (const float*)d_in[12];
  const float* attn_b = (const float*)d_in[13];
  const float* wW     = (const float*)d_in[14];
  const float* w_b    = (const float*)d_in[15];
  float* canvas = (float*)d_out;

  char* wsb = (char*)d_ws;
  size_t off = 0;
  auto alloc = [&](size_t bytes)->char*{
    char* p = wsb + off; off += (bytes + 255) & ~(size_t)255; return p;
  };
  // zeroed state region (must stay contiguous & first)
  float* c_enc    = (float*)alloc(1048576*4);
  float* c_dec    = (float*)alloc(1048576*4);
  u16*   h_enc_bf = (u16*)  alloc(1048576*2);
  u16*   h_dec_bf = (u16*)  alloc(1048576*2);
  float* scalars  = (float*)alloc(4096);
  const size_t state_bytes = off;
  // transients
  float* h_tmp = (float*)alloc(1048576*4);
  float* g_buf = (float*)alloc((size_t)4194304*4);
  u16*   r_bf  = (u16*)  alloc(1048576*2);
  u16*   z_bf  = (u16*)  alloc(262144*2);
  float* zbuf  = (float*)alloc(524288*4);
  float* wbuf  = (float*)alloc(524288*4);
  float* Fx    = (float*)alloc(2097152*4);
  float* Fy    = (float*)alloc(2097152*4);
  float* gamma = (float*)alloc(2048);
  float* xhat  = (float*)alloc((size_t)8388608*4);
  // bf16 weights
  u16* wih_bf  = (u16*)alloc((size_t)33554432*2);
  u16* whh_bf  = (u16*)alloc((size_t)16777216*2);
  u16* dwih_bf = (u16*)alloc((size_t)4194304*2);
  u16* dwhh_bf = (u16*)alloc((size_t)16777216*2);
  u16* muw_bf  = (u16*)alloc((size_t)1048576*2);
  u16* sigw_bf = (u16*)alloc((size_t)1048576*2);
  u16* ww_bf   = (u16*)alloc((size_t)2097152*2);

  // init: zero state + canvas, convert weights
  zero_kernel<<<1024, 256, 0, stream>>>((float*)wsb, (int)(state_bytes/16));
  zero_kernel<<<2048, 256, 0, stream>>>(canvas, (ABF/4)*BSZ);
  cvt_kernel<<<2048, 256, 0, stream>>>(encWih, wih_bf,  33554432/4);
  cvt_kernel<<<2048, 256, 0, stream>>>(encWhh, whh_bf,  16777216/4);
  cvt_kernel<<<1024, 256, 0, stream>>>(decWih, dwih_bf, 4194304/4);
  cvt_kernel<<<2048, 256, 0, stream>>>(decWhh, dwhh_bf, 16777216/4);
  cvt_kernel<<<512,  256, 0, stream>>>(muW,    muw_bf,  1048576/4);
  cvt_kernel<<<512,  256, 0, stream>>>(sigW,   sigw_bf, 1048576/4);
  cvt_kernel<<<512,  256, 0, stream>>>(wW,     ww_bf,   2097152/4);

  for (int t = 0; t < TSTEPS; t++){
    float* sA = scalars + t*8;
    float* sB = scalars + t*8 + 4;
    // read phase (attention from pre-update h_dec)
    attn_kernel<<<512, 256, 0, stream>>>(h_dec_bf, attnW, attn_b, Fx, Fy, gamma);
    xhat_kernel<<<2048, 256, 0, stream>>>(x, canvas, xhat);
    read_kernel<<<512, 256, 0, stream>>>(x, xhat, Fx, Fy, gamma, r_bf);
    // encoder gates: g = [r,h_dec]@Wih^T + h_enc@Whh^T + b
    gemm_bt<128,128><<<dim3(64,4), 256, 0, stream>>>(
        r_bf, HID, wih_bf, 4096, HID,
        h_dec_bf, HID, wih_bf + HID, 4096, HID,
        h_enc_bf, HID, whh_bf, HID, HID,
        enc_b, nullptr, nullptr, 0, g_buf, G4);
    lstm_kernel<<<1024, 256, 0, stream>>>(g_buf, c_enc, h_tmp);
    mdl_reduce1<<<256, 256, 0, stream>>>(h_tmp, sA);
    mdl_reduce2<<<256, 256, 0, stream>>>(h_tmp, sA);
    mdl_scale<<<1024, 256, 0, stream>>>(h_tmp, sA, h_enc_bf);
    // mu | logsigma fused GEMM (n>=512 -> sig_W)
    gemm_bt<64,64><<<dim3(16,8), 256, 0, stream>>>(
        h_enc_bf, HID, muw_bf, HID, HID,
        nullptr, 0, nullptr, 0, 0,
        nullptr, 0, nullptr, 0, 0,
        mu_b, sig_b, sigw_bf, ZD, zbuf, 1024);
    z_kernel<<<256, 256, 0, stream>>>(zbuf, eps + (size_t)t*BSZ*ZD, z_bf);
    // decoder gates
    gemm_bt<128,128><<<dim3(64,4), 256, 0, stream>>>(
        z_bf, ZD, dwih_bf, ZD, ZD,
        h_dec_bf, HID, dwhh_bf, HID, HID,
        nullptr, 0, nullptr, 0, 0,
        dec_b, nullptr, nullptr, 0, g_buf, G4);
    lstm_kernel<<<1024, 256, 0, stream>>>(g_buf, c_dec, h_tmp);
    mdl_reduce1<<<256, 256, 0, stream>>>(h_tmp, sB);
    mdl_reduce2<<<256, 256, 0, stream>>>(h_tmp, sB);
    mdl_scale<<<1024, 256, 0, stream>>>(h_tmp, sB, h_dec_bf);
    // write phase (attention from updated h_dec)
    attn_kernel<<<512, 256, 0, stream>>>(h_dec_bf, attnW, attn_b, Fx, Fy, gamma);
    gemm_bt<64,64><<<dim3(16,8), 256, 0, stream>>>(
        h_dec_bf, HID, ww_bf, HID, HID,
        nullptr, 0, nullptr, 0, 0,
        nullptr, 0, nullptr, 0, 0,
        w_b, nullptr, nullptr, 0, wbuf, 1024);
    write_kernel<<<512, 256, 0, stream>>>(wbuf, Fx, Fy, gamma, canvas);
  }
}

// Round 2
// 5833.867 us; speedup vs baseline: 1.2544x; 1.2544x over previous
//
#include <hip/hip_runtime.h>
#include <math.h>

#define BSZ   512
#define TSTEPS 16
#define HID   2048
#define G4    8192
#define ZD    512
#define ABF   16384
#define LOG2PI_F 1.8378770664093453f

typedef float  f32x4  __attribute__((ext_vector_type(4)));
typedef __bf16 bf16x8 __attribute__((ext_vector_type(8)));
typedef unsigned short u16;
typedef u16 u16x4 __attribute__((ext_vector_type(4)));

__device__ __forceinline__ u16 f2bf(float f){
  union { float f; unsigned u; } v; v.f = f;
  unsigned u = v.u;
  return (u16)((u + 0x7FFFu + ((u >> 16) & 1u)) >> 16);   // RNE
}
__device__ __forceinline__ float bf2f(u16 u){
  union { unsigned u; float f; } v; v.u = ((unsigned)u) << 16; return v.f;
}
__device__ __forceinline__ float sigm(float x){ return 1.f/(1.f + expf(-x)); }

__device__ __forceinline__ void load_lds16(const void* g, void* l){
  __builtin_amdgcn_global_load_lds(
      (const __attribute__((address_space(1))) void*)g,
      (__attribute__((address_space(3))) void*)l, 16, 0, 0);
}

__device__ __forceinline__ float wsum(float v){
  #pragma unroll
  for (int o = 32; o; o >>= 1) v += __shfl_down(v, o, 64);
  return v;
}

// ---------------- utility kernels ----------------
__global__ __launch_bounds__(256) void zero_kernel(float* __restrict__ p, int n4){
  int i = blockIdx.x*256 + threadIdx.x;
  const int st = gridDim.x*256;
  f32x4 z = {0.f,0.f,0.f,0.f};
  for (; i < n4; i += st) ((f32x4*)p)[i] = z;
}

__global__ __launch_bounds__(256) void cvt_kernel(const float* __restrict__ s, u16* __restrict__ d, int n4){
  int i = blockIdx.x*256 + threadIdx.x;
  const int st = gridDim.x*256;
  for (; i < n4; i += st){
    f32x4 v = ((const f32x4*)s)[i];
    u16x4 o;
    o[0]=f2bf(v[0]); o[1]=f2bf(v[1]); o[2]=f2bf(v[2]); o[3]=f2bf(v[3]);
    ((u16x4*)d)[i] = o;
  }
}

// ---------------- fused read: attn + xhat + glimpse ----------------
__global__ __launch_bounds__(256) void read_fused(
    const float* __restrict__ x, const float* __restrict__ canvas,
    const u16* __restrict__ h_dec_bf, const float* __restrict__ attnW,
    const float* __restrict__ attn_b, u16* __restrict__ r_bf)
{
  const int b = blockIdx.x;
  const int tid = threadIdx.x;
  __shared__ float red[4][5];
  __shared__ float prm[5];
  __shared__ float inv[32];
  __shared__ __align__(16) float sF[32*132];
  __shared__ __align__(16) float sT[2][128*33];

  // attn params
  {
    float a0=0,a1=0,a2=0,a3=0,a4=0;
    const u16* h = h_dec_bf + (size_t)b*HID;
    for (int k = tid; k < HID; k += 256){
      const float hv = bf2f(h[k]);
      a0 += hv*attnW[k];
      a1 += hv*attnW[HID + k];
      a2 += hv*attnW[2*HID + k];
      a3 += hv*attnW[3*HID + k];
      a4 += hv*attnW[4*HID + k];
    }
    a0 = wsum(a0); a1 = wsum(a1); a2 = wsum(a2); a3 = wsum(a3); a4 = wsum(a4);
    if ((tid & 63) == 0){
      const int w = tid >> 6;
      red[w][0]=a0; red[w][1]=a1; red[w][2]=a2; red[w][3]=a3; red[w][4]=a4;
    }
  }
  __syncthreads();
  if (tid < 5){
    const float p = red[0][tid]+red[1][tid]+red[2][tid]+red[3][tid] + attn_b[tid];
    float v;
    if (tid <= 1)      v = 64.5f*(p + 1.f);
    else if (tid == 2) v = 1.f/(2.f*expf(p));       // i2s
    else if (tid == 3) v = (127.f/31.f)*expf(p);    // delta
    else               v = expf(p);                  // gamma
    prm[tid] = v;
  }
  __syncthreads();
  const float gx = prm[0], gy = prm[1], i2s = prm[2], dl = prm[3], gm = prm[4];

  auto genF = [&](float g0){
    for (int i = tid; i < 4096; i += 256){
      const int n = i >> 7, a = i & 127;
      const float mu = g0 + ((float)n - 16.5f)*dl;
      const float t = ((float)a - mu)*i2s;
      sF[n*132 + a] = expf(-t*t);
    }
    __syncthreads();
    if (tid < 32){
      float ssum = 0.f;
      for (int a = 0; a < 128; a++) ssum += sF[tid*132 + a];
      inv[tid] = 1.f/(ssum + 1e-9f);
    }
    __syncthreads();
    for (int i = tid; i < 4096; i += 256)
      sF[(i >> 7)*132 + (i & 127)] *= inv[i >> 7];
    __syncthreads();
  };

  genF(gx);   // Fx normalized

  // stage 1: T[B][m] for both x and xhat (xhat computed on the fly)
  const int Bg = tid & 31;
  const int mg = tid >> 5;
  {
    const float* xb = x      + (size_t)b*ABF;
    const float* cb = canvas + (size_t)b*ABF;
    float acc0[4][4] = {}, acc1[4][4] = {};
    for (int a = 0; a < 128; a += 4){
      f32x4 fx4[4];
      #pragma unroll
      for (int j = 0; j < 4; j++) fx4[j] = *(const f32x4*)&sF[(mg*4 + j)*132 + a];
      #pragma unroll
      for (int i = 0; i < 4; i++){
        const int row = (Bg + 32*i)*128 + a;
        f32x4 xv = *(const f32x4*)&xb[row];
        f32x4 cv = *(const f32x4*)&cb[row];
        f32x4 xh;
        #pragma unroll
        for (int k = 0; k < 4; k++) xh[k] = xv[k] - sigm(cv[k]);
        #pragma unroll
        for (int j = 0; j < 4; j++){
          acc0[i][j] += xv[0]*fx4[j][0] + xv[1]*fx4[j][1] + xv[2]*fx4[j][2] + xv[3]*fx4[j][3];
          acc1[i][j] += xh[0]*fx4[j][0] + xh[1]*fx4[j][1] + xh[2]*fx4[j][2] + xh[3]*fx4[j][3];
        }
      }
    }
    #pragma unroll
    for (int i = 0; i < 4; i++)
      #pragma unroll
      for (int j = 0; j < 4; j++){
        sT[0][(Bg + 32*i)*33 + mg*4 + j] = acc0[i][j];
        sT[1][(Bg + 32*i)*33 + mg*4 + j] = acc1[i][j];
      }
  }
  __syncthreads();

  genF(gy);   // Fy normalized (sF reused)

  // stage 2: r[n][m] = sum_B Fy[n][B] T[B][m]
  const int mat = tid >> 7;
  const int rem = tid & 127;
  const int ng  = rem >> 4;
  const int mg2 = rem & 15;
  float acc[4][2] = {};
  for (int B4 = 0; B4 < 128; B4 += 4){
    f32x4 fy4[4];
    #pragma unroll
    for (int i = 0; i < 4; i++) fy4[i] = *(const f32x4*)&sF[(ng*4 + i)*132 + B4];
    #pragma unroll
    for (int k = 0; k < 4; k++){
      const float t0 = sT[mat][(B4 + k)*33 + mg2*2 + 0];
      const float t1 = sT[mat][(B4 + k)*33 + mg2*2 + 1];
      #pragma unroll
      for (int i = 0; i < 4; i++){
        acc[i][0] += fy4[i][k]*t0;
        acc[i][1] += fy4[i][k]*t1;
      }
    }
  }
  #pragma unroll
  for (int i = 0; i < 4; i++)
    #pragma unroll
    for (int j = 0; j < 2; j++)
      r_bf[(size_t)b*2048 + mat*1024 + (ng*4 + i)*32 + mg2*2 + j] = f2bf(acc[i][j]*gm);
}

// ---------------- bf16 B^T GEMM, split-K via blockIdx.z ----------------
struct Slice { const u16* A; const u16* W; const u16* Whi; float* C; int lda, ldw, K, pad; };
struct Slices { Slice s[4]; };

template<int BM, int BN>
__global__ __launch_bounds__(256) void gemm_bt(Slices sl, int nsplit, int ldc)
{
  constexpr int BK = 64;
  constexpr int FI = BM/32;
  constexpr int FJ = BN/32;
  __shared__ __align__(16) u16 Asm[BM*BK];
  __shared__ __align__(16) u16 Bsm[BN*BK];
  const int tid  = threadIdx.x;
  const int wave = tid >> 6;
  const int lane = tid & 63;
  const int wm = wave & 1, wn = wave >> 1;
  const int m0 = blockIdx.y * BM;
  const int n0 = blockIdx.x * BN;
  const Slice& sp = sl.s[blockIdx.z];
  const u16* Ap = sp.A;
  const u16* Wp = sp.W;
  const int lda = sp.lda, ldw = sp.ldw, K = sp.K;
  if (nsplit > 0 && n0 >= nsplit) Wp = sp.Whi - (size_t)nsplit * ldw;
  float* C = sp.C;

  f32x4 acc[FI][FJ];
  #pragma unroll
  for (int i = 0; i < FI; i++)
    #pragma unroll
    for (int j = 0; j < FJ; j++) acc[i][j] = (f32x4){0.f,0.f,0.f,0.f};

  const int lr = lane & 15;
  const int lq = lane >> 4;

  for (int kt = 0; kt < K; kt += BK){
    __syncthreads();
    constexpr int NCA = BM*BK/8;
    #pragma unroll
    for (int it = 0; it < NCA/256; it++){
      const int cb = it*256 + wave*64;
      const int c  = cb + lane;
      const int row = c >> 3;
      const int c8  = (c & 7) ^ (row & 7);
      load_lds16(Ap + (size_t)(m0 + row)*lda + kt + c8*8, &Asm[cb*8]);
    }
    constexpr int NCB = BN*BK/8;
    #pragma unroll
    for (int it = 0; it < NCB/256; it++){
      const int cb = it*256 + wave*64;
      const int c  = cb + lane;
      const int row = c >> 3;
      const int c8  = (c & 7) ^ (row & 7);
      load_lds16(Wp + (size_t)(n0 + row)*ldw + kt + c8*8, &Bsm[cb*8]);
    }
    __syncthreads();
    #pragma unroll
    for (int ks = 0; ks < 2; ks++){
      bf16x8 af[FI], bfr[FJ];
      #pragma unroll
      for (int i = 0; i < FI; i++){
        const int row = wm*(BM/2) + i*16 + lr;
        const int xx = (ks*4 + lq) ^ (row & 7);
        af[i] = *(const bf16x8*)&Asm[row*BK + xx*8];
      }
      #pragma unroll
      for (int j = 0; j < FJ; j++){
        const int row = wn*(BN/2) + j*16 + lr;
        const int xx = (ks*4 + lq) ^ (row & 7);
        bfr[j] = *(const bf16x8*)&Bsm[row*BK + xx*8];
      }
      #pragma unroll
      for (int i = 0; i < FI; i++)
        #pragma unroll
        for (int j = 0; j < FJ; j++)
          acc[i][j] = __builtin_amdgcn_mfma_f32_16x16x32_bf16(af[i], bfr[j], acc[i][j], 0, 0, 0);
    }
  }
  // C/D layout: col=lane&15, row=(lane>>4)*4+reg (m89-verified)
  #pragma unroll
  for (int i = 0; i < FI; i++){
    const int gm = m0 + wm*(BM/2) + i*16 + lq*4;
    #pragma unroll
    for (int j = 0; j < FJ; j++){
      const int gn = n0 + wn*(BN/2) + j*16 + lr;
      #pragma unroll
      for (int r = 0; r < 4; r++)
        C[(size_t)(gm + r)*ldc + gn] = acc[i][j][r];
    }
  }
}

// ---------------- LSTM pointwise (+bias +3-way partial sum +block stats) ----------------
__global__ __launch_bounds__(256) void lstm_kernel(
    const float* __restrict__ g, const float* __restrict__ bias,
    float* __restrict__ c, float* __restrict__ h, float* __restrict__ ps)
{
  const int idx = blockIdx.x*256 + threadIdx.x;  // < 262144
  const int m = idx >> 9;
  const int q = idx & 511;
  const size_t gb = (size_t)m*G4 + q*4;
  const float* g1 = g + 4194304;
  const float* g2 = g + 2*4194304;
  f32x4 gi = *(const f32x4*)&g[gb]         + *(const f32x4*)&g1[gb]         + *(const f32x4*)&g2[gb]         + *(const f32x4*)&bias[q*4];
  f32x4 gf = *(const f32x4*)&g[gb+HID]     + *(const f32x4*)&g1[gb+HID]     + *(const f32x4*)&g2[gb+HID]     + *(const f32x4*)&bias[HID+q*4];
  f32x4 gg = *(const f32x4*)&g[gb+2*HID]   + *(const f32x4*)&g1[gb+2*HID]   + *(const f32x4*)&g2[gb+2*HID]   + *(const f32x4*)&bias[2*HID+q*4];
  f32x4 go = *(const f32x4*)&g[gb+3*HID]   + *(const f32x4*)&g1[gb+3*HID]   + *(const f32x4*)&g2[gb+3*HID]   + *(const f32x4*)&bias[3*HID+q*4];
  const size_t cb = (size_t)m*HID + q*4;
  f32x4 cv = *(const f32x4*)&c[cb];
  f32x4 cn, hn;
  #pragma unroll
  for (int k = 0; k < 4; k++){
    const float ck = sigm(gf[k])*cv[k] + sigm(gi[k])*tanhf(gg[k]);
    cn[k] = ck;
    hn[k] = sigm(go[k])*tanhf(ck);
  }
  *(f32x4*)&c[cb] = cn;
  *(f32x4*)&h[cb] = hn;
  // block partial stats of h
  float s1 = hn[0]+hn[1]+hn[2]+hn[3];
  float s2 = hn[0]*hn[0]+hn[1]*hn[1]+hn[2]*hn[2]+hn[3]*hn[3];
  s1 = wsum(s1); s2 = wsum(s2);
  __shared__ float r1[4], r2[4];
  const int w = threadIdx.x >> 6;
  if ((threadIdx.x & 63) == 0){ r1[w] = s1; r2[w] = s2; }
  __syncthreads();
  if (threadIdx.x == 0){
    ps[blockIdx.x]        = r1[0]+r1[1]+r1[2]+r1[3];
    ps[1024 + blockIdx.x] = r2[0]+r2[1]+r2[2]+r2[3];
  }
}

// ---------------- MDL sum-exp pass ----------------
__global__ __launch_bounds__(256) void sumexp_kernel(
    const float* __restrict__ h, const float* __restrict__ ps, float* __restrict__ pe)
{
  const int tid = threadIdx.x;
  float t1 = 0.f, t2 = 0.f;
  for (int i = tid; i < 1024; i += 256){ t1 += ps[i]; t2 += ps[1024 + i]; }
  t1 = wsum(t1); t2 = wsum(t2);
  __shared__ float r1[4], r2[4];
  const int w = tid >> 6;
  if ((tid & 63) == 0){ r1[w] = t1; r2[w] = t2; }
  __syncthreads();
  __shared__ float mh[2];
  if (tid == 0){
    const float S1 = r1[0]+r1[1]+r1[2]+r1[3];
    const float S2 = r2[0]+r2[1]+r2[2]+r2[3];
    const float mean = S1*(1.f/1048576.f);
    const float var  = (S2 - 1048576.f*mean*mean)*(1.f/1048575.f);
    mh[0] = mean; mh[1] = 1.f/sqrtf(var);
  }
  __syncthreads();
  const float mean = mh[0], istd = mh[1];
  float se = 0.f;
  for (int i = blockIdx.x*256 + tid; i < (1<<18); i += 256*256){
    f32x4 v = ((const f32x4*)h)[i];
    #pragma unroll
    for (int k = 0; k < 4; k++){
      const float u = (v[k] - mean)*istd;
      se += expf(-0.5f*u*u);
    }
  }
  se = wsum(se);
  __shared__ float r3[4];
  if ((tid & 63) == 0) r3[w] = se;
  __syncthreads();
  if (tid == 0) pe[blockIdx.x] = r3[0]+r3[1]+r3[2]+r3[3];
}

// ---------------- MDL scale ----------------
__global__ __launch_bounds__(256) void scale_kernel(
    const float* __restrict__ h, const float* __restrict__ ps,
    const float* __restrict__ pe, u16* __restrict__ hb)
{
  const int tid = threadIdx.x;
  float t1 = 0.f, t2 = 0.f;
  for (int i = tid; i < 1024; i += 256){ t1 += ps[i]; t2 += ps[1024 + i]; }
  float t3 = pe[tid];
  t1 = wsum(t1); t2 = wsum(t2); t3 = wsum(t3);
  __shared__ float r1[4], r2[4], r3[4];
  const int w = tid >> 6;
  if ((tid & 63) == 0){ r1[w] = t1; r2[w] = t2; r3[w] = t3; }
  __syncthreads();
  __shared__ float lsh;
  if (tid == 0){
    const float S1 = r1[0]+r1[1]+r1[2]+r1[3];
    const float S2 = r2[0]+r2[1]+r2[2]+r2[3];
    const float SE = r3[0]+r3[1]+r3[2]+r3[3];
    const float mean = S1*(1.f/1048576.f);
    const float var  = (S2 - 1048576.f*mean*mean)*(1.f/1048575.f);
    const float stdv = sqrtf(var);
    const float lse = logf(SE) - logf(stdv) - 0.5f*LOG2PI_F;
    lsh = fmaxf(-lse, 0.f) + log1pf(expf(-fabsf(lse)));   // logaddexp(0,lse)-lse
  }
  __syncthreads();
  const float l = lsh;
  const int i = blockIdx.x*256 + tid;   // < 262144
  f32x4 v = ((const f32x4*)h)[i];
  u16x4 o;
  #pragma unroll
  for (int k = 0; k < 4; k++) o[k] = f2bf(v[k]*l);
  ((u16x4*)hb)[i] = o;
}

// ---------------- z = mu + exp(logsig)*eps (sums 4 split-K partials) ----------------
__global__ __launch_bounds__(256) void z_kernel(
    const float* __restrict__ zp, const float* __restrict__ mu_b,
    const float* __restrict__ sig_b, const float* __restrict__ ep, u16* __restrict__ zo)
{
  const int idx = blockIdx.x*256 + threadIdx.x;  // < 65536
  const int m = idx >> 7;
  const int q = idx & 127;
  const size_t base = (size_t)m*1024 + q*4;
  f32x4 mu = *(const f32x4*)&zp[base] + *(const f32x4*)&zp[524288 + base]
           + *(const f32x4*)&zp[2*524288 + base] + *(const f32x4*)&zp[3*524288 + base]
           + *(const f32x4*)&mu_b[q*4];
  f32x4 ls = *(const f32x4*)&zp[base+512] + *(const f32x4*)&zp[524288 + base+512]
           + *(const f32x4*)&zp[2*524288 + base+512] + *(const f32x4*)&zp[3*524288 + base+512]
           + *(const f32x4*)&sig_b[q*4];
  f32x4 ev = *(const f32x4*)&ep[(size_t)m*512 + q*4];
  u16x4 o;
  #pragma unroll
  for (int k = 0; k < 4; k++) o[k] = f2bf(mu[k] + expf(ls[k])*ev[k]);
  ((u16x4*)zo)[idx] = o;
}

// ---------------- fused write: attn + canvas += (Fy^T @ w @ Fx)/gamma ----------------
__global__ __launch_bounds__(256) void write_fused(
    const float* __restrict__ wp, const float* __restrict__ w_b,
    const u16* __restrict__ h_dec_bf, const float* __restrict__ attnW,
    const float* __restrict__ attn_b, float* __restrict__ canvas)
{
  const int b = blockIdx.x;
  const int tid = threadIdx.x;
  __shared__ float red[4][5];
  __shared__ float prm[5];
  __shared__ float inv[32];
  __shared__ float sW[1024];
  __shared__ __align__(16) float sF[32*132];
  __shared__ float sU[128*33];

  {
    float a0=0,a1=0,a2=0,a3=0,a4=0;
    const u16* h = h_dec_bf + (size_t)b*HID;
    for (int k = tid; k < HID; k += 256){
      const float hv = bf2f(h[k]);
      a0 += hv*attnW[k];
      a1 += hv*attnW[HID + k];
      a2 += hv*attnW[2*HID + k];
      a3 += hv*attnW[3*HID + k];
      a4 += hv*attnW[4*HID + k];
    }
    a0 = wsum(a0); a1 = wsum(a1); a2 = wsum(a2); a3 = wsum(a3); a4 = wsum(a4);
    if ((tid & 63) == 0){
      const int w = tid >> 6;
      red[w][0]=a0; red[w][1]=a1; red[w][2]=a2; red[w][3]=a3; red[w][4]=a4;
    }
  }
  for (int i = tid; i < 1024; i += 256)
    sW[i] = wp[(size_t)b*1024 + i] + wp[524288 + (size_t)b*1024 + i]
          + wp[2*524288 + (size_t)b*1024 + i] + wp[3*524288 + (size_t)b*1024 + i] + w_b[i];
  __syncthreads();
  if (tid < 5){
    const float p = red[0][tid]+red[1][tid]+red[2][tid]+red[3][tid] + attn_b[tid];
    float v;
    if (tid <= 1)      v = 64.5f*(p + 1.f);
    else if (tid == 2) v = 1.f/(2.f*expf(p));
    else if (tid == 3) v = (127.f/31.f)*expf(p);
    else               v = expf(p);
    prm[tid] = v;
  }
  __syncthreads();
  const float gx = prm[0], gy = prm[1], i2s = prm[2], dl = prm[3], gm = prm[4];

  auto genF = [&](float g0){
    for (int i = tid; i < 4096; i += 256){
      const int n = i >> 7, a = i & 127;
      const float mu = g0 + ((float)n - 16.5f)*dl;
      const float t = ((float)a - mu)*i2s;
      sF[n*132 + a] = expf(-t*t);
    }
    __syncthreads();
    if (tid < 32){
      float ssum = 0.f;
      for (int a = 0; a < 128; a++) ssum += sF[tid*132 + a];
      inv[tid] = 1.f/(ssum + 1e-9f);
    }
    __syncthreads();
    for (int i = tid; i < 4096; i += 256)
      sF[(i >> 7)*132 + (i & 127)] *= inv[i >> 7];
    __syncthreads();
  };

  genF(gy);   // Fy
  // stage 1: U[B][m] = sum_n Fy[n][B] w[n][m]
  {
    const int Bg = tid & 31, mg = tid >> 5;
    float acc[4][4] = {};
    for (int n = 0; n < 32; n++){
      float fy[4], wv[4];
      #pragma unroll
      for (int i = 0; i < 4; i++) fy[i] = sF[n*132 + Bg + 32*i];
      #pragma unroll
      for (int j = 0; j < 4; j++) wv[j] = sW[n*32 + mg*4 + j];
      #pragma unroll
      for (int i = 0; i < 4; i++)
        #pragma unroll
        for (int j = 0; j < 4; j++) acc[i][j] += fy[i]*wv[j];
    }
    #pragma unroll
    for (int i = 0; i < 4; i++)
      #pragma unroll
      for (int j = 0; j < 4; j++)
        sU[(Bg + 32*i)*33 + mg*4 + j] = acc[i][j];
  }
  __syncthreads();
  genF(gx);   // Fx (sF reused)
  // stage 2: canvas[B][a] += sum_m U[B][m] Fx[m][a] / gamma
  {
    const int Bg = tid & 31, ag = tid >> 5;
    float acc[64];
    #pragma unroll
    for (int k = 0; k < 64; k++) acc[k] = 0.f;
    for (int mm = 0; mm < 32; mm++){
      float u[4];
      #pragma unroll
      for (int i = 0; i < 4; i++) u[i] = sU[(Bg + 32*i)*33 + mm];
      f32x4 fx[4];
      #pragma unroll
      for (int k = 0; k < 4; k++) fx[k] = *(const f32x4*)&sF[mm*132 + ag*16 + k*4];
      #pragma unroll
      for (int i = 0; i < 4; i++)
        #pragma unroll
        for (int k = 0; k < 4; k++)
          #pragma unroll
          for (int cc = 0; cc < 4; cc++)
            acc[i*16 + k*4 + cc] += u[i]*fx[k][cc];
    }
    const float ig = 1.f/gm;
    #pragma unroll
    for (int i = 0; i < 4; i++){
      const int B_ = Bg + 32*i;
      #pragma unroll
      for (int k = 0; k < 4; k++){
        float* cp = &canvas[(size_t)b*ABF + B_*128 + ag*16 + k*4];
        f32x4 cv = *(const f32x4*)cp;
        #pragma unroll
        for (int cc = 0; cc < 4; cc++) cv[cc] += acc[i*16 + k*4 + cc]*ig;
        *(f32x4*)cp = cv;
      }
    }
  }
}

// ---------------- host ----------------
extern "C" void kernel_launch(void* const* d_in, const int* in_sizes, int n_in,
                              void* d_out, int out_size, void* d_ws, size_t ws_size,
                              hipStream_t stream)
{
  (void)in_sizes; (void)n_in; (void)out_size; (void)ws_size;
  const float* x      = (const float*)d_in[0];
  const float* eps    = (const float*)d_in[1];
  const float* encWih = (const float*)d_in[2];
  const float* encWhh = (const float*)d_in[3];
  const float* enc_b  = (const float*)d_in[4];
  const float* decWih = (const float*)d_in[5];
  const float* decWhh = (const float*)d_in[6];
  const float* dec_b  = (const float*)d_in[7];
  const float* muW    = (const float*)d_in[8];
  const float* mu_b   = (const float*)d_in[9];
  const float* sigW   = (const float*)d_in[10];
  const float* sig_b  = (const float*)d_in[11];
  const float* attnW  = (const float*)d_in[12];
  const float* attn_b = (const float*)d_in[13];
  const float* wW     = (const float*)d_in[14];
  const float* w_b    = (const float*)d_in[15];
  float* canvas = (float*)d_out;

  char* wsb = (char*)d_ws;
  size_t off = 0;
  auto alloc = [&](size_t bytes)->char*{
    char* p = wsb + off; off += (bytes + 255) & ~(size_t)255; return p;
  };
  // zeroed state region (contiguous, first)
  float* c_enc    = (float*)alloc(1048576*4);
  float* c_dec    = (float*)alloc(1048576*4);
  u16*   h_enc_bf = (u16*)  alloc(1048576*2);
  u16*   h_dec_bf = (u16*)  alloc(1048576*2);
  const size_t state_bytes = off;
  // transients
  float* ps    = (float*)alloc(2304*4);          // [0..1023]=s1, [1024..2047]=s2, +pe elsewhere
  float* pe    = (float*)alloc(256*4);
  float* h_tmp = (float*)alloc(1048576*4);
  float* g_buf = (float*)alloc((size_t)3*4194304*4);   // 3 split-K partials
  u16*   r_bf  = (u16*)  alloc(1048576*2);
  u16*   z_bf  = (u16*)  alloc(262144*2);
  float* zbuf  = (float*)alloc((size_t)4*524288*4);    // 4 partials
  float* wbuf  = (float*)alloc((size_t)4*524288*4);    // 4 partials
  // bf16 weights
  u16* wih_bf  = (u16*)alloc((size_t)33554432*2);
  u16* whh_bf  = (u16*)alloc((size_t)16777216*2);
  u16* dwih_bf = (u16*)alloc((size_t)4194304*2);
  u16* dwhh_bf = (u16*)alloc((size_t)16777216*2);
  u16* muw_bf  = (u16*)alloc((size_t)1048576*2);
  u16* sigw_bf = (u16*)alloc((size_t)1048576*2);
  u16* ww_bf   = (u16*)alloc((size_t)2097152*2);

  // init
  zero_kernel<<<1024, 256, 0, stream>>>((float*)wsb, (int)(state_bytes/16));
  zero_kernel<<<2048, 256, 0, stream>>>(canvas, (ABF/4)*BSZ);
  cvt_kernel<<<2048, 256, 0, stream>>>(encWih, wih_bf,  33554432/4);
  cvt_kernel<<<2048, 256, 0, stream>>>(encWhh, whh_bf,  16777216/4);
  cvt_kernel<<<1024, 256, 0, stream>>>(decWih, dwih_bf, 4194304/4);
  cvt_kernel<<<2048, 256, 0, stream>>>(decWhh, dwhh_bf, 16777216/4);
  cvt_kernel<<<512,  256, 0, stream>>>(muW,    muw_bf,  1048576/4);
  cvt_kernel<<<512,  256, 0, stream>>>(sigW,   sigw_bf, 1048576/4);
  cvt_kernel<<<512,  256, 0, stream>>>(wW,     ww_bf,   2097152/4);

  float* g0 = g_buf;
  float* g1 = g_buf + 4194304;
  float* g2 = g_buf + 2*4194304;

  Slices enc_sl = {};
  enc_sl.s[0] = { r_bf,            wih_bf,          nullptr, g0, HID, 2*HID, HID, 0 };
  enc_sl.s[1] = { h_dec_bf,        wih_bf + HID,    nullptr, g1, HID, 2*HID, HID, 0 };
  enc_sl.s[2] = { h_enc_bf,        whh_bf,          nullptr, g2, HID, HID,   HID, 0 };

  Slices dec_sl = {};
  dec_sl.s[0] = { z_bf,            dwih_bf,         nullptr, g0, ZD,  ZD,    ZD,   0 };
  dec_sl.s[1] = { h_dec_bf,        dwhh_bf,         nullptr, g1, HID, HID,   1024, 0 };
  dec_sl.s[2] = { h_dec_bf + 1024, dwhh_bf + 1024,  nullptr, g2, HID, HID,   1024, 0 };

  Slices ms_sl = {}, w_sl = {};
  for (int k = 0; k < 4; k++){
    ms_sl.s[k] = { h_enc_bf + 512*k, muw_bf + 512*k, sigw_bf + 512*k, zbuf + (size_t)k*524288, HID, HID, 512, 0 };
    w_sl.s[k]  = { h_dec_bf + 512*k, ww_bf  + 512*k, nullptr,         wbuf + (size_t)k*524288, HID, HID, 512, 0 };
  }

  for (int t = 0; t < TSTEPS; t++){
    // read phase (attn from pre-update h_dec, xhat fused)
    read_fused<<<512, 256, 0, stream>>>(x, canvas, h_dec_bf, attnW, attn_b, r_bf);
    // encoder gates, split-K 3-way
    gemm_bt<128,128><<<dim3(64,4,3), 256, 0, stream>>>(enc_sl, 0, G4);
    lstm_kernel<<<1024, 256, 0, stream>>>(g_buf, enc_b, c_enc, h_tmp, ps);
    sumexp_kernel<<<256, 256, 0, stream>>>(h_tmp, ps, pe);
    scale_kernel<<<1024, 256, 0, stream>>>(h_tmp, ps, pe, h_enc_bf);
    // mu | logsigma fused GEMM, split-K 4-way (n>=512 -> sig_W)
    gemm_bt<64,64><<<dim3(16,8,4), 256, 0, stream>>>(ms_sl, 512, 1024);
    z_kernel<<<256, 256, 0, stream>>>(zbuf, mu_b, sig_b, eps + (size_t)t*BSZ*ZD, z_bf);
    // decoder gates, split-K 3-way
    gemm_bt<128,128><<<dim3(64,4,3), 256, 0, stream>>>(dec_sl, 0, G4);
    lstm_kernel<<<1024, 256, 0, stream>>>(g_buf, dec_b, c_dec, h_tmp, ps);
    sumexp_kernel<<<256, 256, 0, stream>>>(h_tmp, ps, pe);
    scale_kernel<<<1024, 256, 0, stream>>>(h_tmp, ps, pe, h_dec_bf);
    // write phase (attn from updated h_dec)
    gemm_bt<64,64><<<dim3(16,8,4), 256, 0, stream>>>(w_sl, 0, 1024);
    write_fused<<<512, 256, 0, stream>>>(wbuf, w_b, h_dec_bf, attnW, attn_b, canvas);
  }
}

// Round 3
// 4543.224 us; speedup vs baseline: 1.6108x; 1.2841x over previous
//
#include <hip/hip_runtime.h>
#include <math.h>

#define BSZ   512
#define TSTEPS 16
#define HID   2048
#define G4    8192
#define ZD    512
#define ABF   16384
#define LOG2PI_F 1.8378770664093453f

typedef float  f32x4  __attribute__((ext_vector_type(4)));
typedef __bf16 bf16x8 __attribute__((ext_vector_type(8)));
typedef unsigned short u16;
typedef u16 u16x4 __attribute__((ext_vector_type(4)));
typedef u16 u16x8v __attribute__((ext_vector_type(8)));
union bfcast { u16x8v u; bf16x8 b; };

__device__ __forceinline__ u16 f2bf(float f){
  union { float f; unsigned u; } v; v.f = f;
  unsigned u = v.u;
  return (u16)((u + 0x7FFFu + ((u >> 16) & 1u)) >> 16);   // RNE
}
__device__ __forceinline__ float bf2f(u16 u){
  union { unsigned u; float f; } v; v.u = ((unsigned)u) << 16; return v.f;
}
__device__ __forceinline__ float sigm(float x){ return 1.f/(1.f + expf(-x)); }

__device__ __forceinline__ void load_lds16(const void* g, void* l){
  __builtin_amdgcn_global_load_lds(
      (const __attribute__((address_space(1))) void*)g,
      (__attribute__((address_space(3))) void*)l, 16, 0, 0);
}

__device__ __forceinline__ float wsum(float v){
  #pragma unroll
  for (int o = 32; o; o >>= 1) v += __shfl_down(v, o, 64);
  return v;
}

// ---------------- utility kernels ----------------
__global__ __launch_bounds__(256) void zero_kernel(float* __restrict__ p, int n4){
  int i = blockIdx.x*256 + threadIdx.x;
  const int st = gridDim.x*256;
  f32x4 z = {0.f,0.f,0.f,0.f};
  for (; i < n4; i += st) ((f32x4*)p)[i] = z;
}

__global__ __launch_bounds__(256) void cvt_kernel(const float* __restrict__ s, u16* __restrict__ d, int n4){
  int i = blockIdx.x*256 + threadIdx.x;
  const int st = gridDim.x*256;
  for (; i < n4; i += st){
    f32x4 v = ((const f32x4*)s)[i];
    u16x4 o;
    o[0]=f2bf(v[0]); o[1]=f2bf(v[1]); o[2]=f2bf(v[2]); o[3]=f2bf(v[3]);
    ((u16x4*)d)[i] = o;
  }
}

// ---------------- fused read: attn + xhat + glimpse (MFMA) ----------------
__global__ __launch_bounds__(256) void read_fused(
    const u16* __restrict__ x_bf, const float* __restrict__ canvas,
    const u16* __restrict__ h_dec_bf, const float* __restrict__ attnW,
    const float* __restrict__ attn_b, u16* __restrict__ r_bf)
{
  const int b = blockIdx.x;
  const int tid = threadIdx.x;
  const int wave = tid >> 6;
  const int lane = tid & 63;
  const int lr = lane & 15;
  const int lq = lane >> 4;
  __shared__ float red[4][5];
  __shared__ float prm[5];
  __shared__ float rowsum[32][9];
  __shared__ __align__(16) u16 Fxb[32*128];   // row n, 16B-chunk c stored at c^(n&7)
  __shared__ __align__(16) u16 Fyb[32*128];
  __shared__ __align__(16) u16 Ttx[32*136];   // T[m][B], pad to 136
  __shared__ __align__(16) u16 Ttxh[32*136];

  // ---- attn params ----
  {
    float a0=0,a1=0,a2=0,a3=0,a4=0;
    const u16* h = h_dec_bf + (size_t)b*HID;
    for (int k = tid; k < HID; k += 256){
      const float hv = bf2f(h[k]);
      a0 += hv*attnW[k];
      a1 += hv*attnW[HID + k];
      a2 += hv*attnW[2*HID + k];
      a3 += hv*attnW[3*HID + k];
      a4 += hv*attnW[4*HID + k];
    }
    a0 = wsum(a0); a1 = wsum(a1); a2 = wsum(a2); a3 = wsum(a3); a4 = wsum(a4);
    if (lane == 0){
      red[wave][0]=a0; red[wave][1]=a1; red[wave][2]=a2; red[wave][3]=a3; red[wave][4]=a4;
    }
  }
  __syncthreads();
  if (tid < 5){
    const float p = red[0][tid]+red[1][tid]+red[2][tid]+red[3][tid] + attn_b[tid];
    float v;
    if (tid <= 1)      v = 64.5f*(p + 1.f);
    else if (tid == 2) v = 1.f/(2.f*expf(p));       // i2s
    else if (tid == 3) v = (127.f/31.f)*expf(p);    // delta
    else               v = expf(p);                  // gamma
    prm[tid] = v;
  }
  __syncthreads();
  const float gx = prm[0], gy = prm[1], i2s = prm[2], dl = prm[3], gm = prm[4];

  // ---- F generation (bf16, swizzled) ----
  auto genF = [&](float g0, u16* dst){
    const int rr = tid >> 3;
    const int asub = tid & 7;
    const float mu = g0 + ((float)rr - 16.5f)*dl;
    float s = 0.f;
    for (int a = asub*16; a < asub*16 + 16; a++){
      const float t = ((float)a - mu)*i2s;
      s += expf(-t*t);
    }
    rowsum[rr][asub] = s;
    __syncthreads();
    if (tid < 32){
      float tot = 0.f;
      #pragma unroll
      for (int j = 0; j < 8; j++) tot += rowsum[tid][j];
      rowsum[tid][8] = 1.f/(tot + 1e-9f);
    }
    __syncthreads();
    for (int i = tid; i < 4096; i += 256){
      const int n = i >> 7, a = i & 127;
      const float mu2 = g0 + ((float)n - 16.5f)*dl;
      const float t = ((float)a - mu2)*i2s;
      const float v = expf(-t*t)*rowsum[n][8];
      const int pos = (a >> 3) ^ (n & 7);
      dst[n*128 + pos*8 + (a & 7)] = f2bf(v);
    }
    __syncthreads();
  };
  genF(gx, Fxb);
  genF(gy, Fyb);

  // ---- stage 1: T[B][m] = sum_a img[B][a] Fx[m][a], per wave: B-rows [32w,32w+32) ----
  const u16*   xb = x_bf   + (size_t)b*ABF;
  const float* cb = canvas + (size_t)b*ABF;
  f32x4 Cx[2][2], Ch[2][2];
  #pragma unroll
  for (int i = 0; i < 2; i++)
    #pragma unroll
    for (int j = 0; j < 2; j++){ Cx[i][j] = (f32x4){0,0,0,0}; Ch[i][j] = (f32x4){0,0,0,0}; }

  #pragma unroll
  for (int mt = 0; mt < 2; mt++){
    const int row = wave*32 + mt*16 + lr;
    bfcast ax[4], ah[4];
    #pragma unroll
    for (int ks = 0; ks < 4; ks++){
      const int base = row*128 + ks*32 + lq*8;
      ax[ks].u = *(const u16x8v*)&xb[base];
      f32x4 c0 = *(const f32x4*)&cb[base];
      f32x4 c1 = *(const f32x4*)&cb[base + 4];
      #pragma unroll
      for (int j = 0; j < 4; j++){
        ah[ks].u[j]   = f2bf(bf2f(ax[ks].u[j])   - sigm(c0[j]));
        ah[ks].u[4+j] = f2bf(bf2f(ax[ks].u[4+j]) - sigm(c1[j]));
      }
    }
    #pragma unroll
    for (int nt = 0; nt < 2; nt++){
      #pragma unroll
      for (int ks = 0; ks < 4; ks++){
        const int pos = (ks*4 + lq) ^ (lr & 7);
        bf16x8 bf_ = *(const bf16x8*)&Fxb[(nt*16 + lr)*128 + pos*8];
        Cx[mt][nt] = __builtin_amdgcn_mfma_f32_16x16x32_bf16(ax[ks].b, bf_, Cx[mt][nt], 0, 0, 0);
        Ch[mt][nt] = __builtin_amdgcn_mfma_f32_16x16x32_bf16(ah[ks].b, bf_, Ch[mt][nt], 0, 0, 0);
      }
    }
  }
  // write T to LDS as bf16 [m][B] (C-layout: col=lane&15 -> m, row=lq*4+r -> B)
  #pragma unroll
  for (int mt = 0; mt < 2; mt++)
    #pragma unroll
    for (int nt = 0; nt < 2; nt++)
      #pragma unroll
      for (int r = 0; r < 4; r++){
        const int m  = nt*16 + lr;
        const int B_ = wave*32 + mt*16 + lq*4 + r;
        Ttx[m*136 + B_]  = f2bf(Cx[mt][nt][r]);
        Ttxh[m*136 + B_] = f2bf(Ch[mt][nt][r]);
      }
  __syncthreads();

  // ---- stage 2: r[n][m] = sum_B Fy[n][B] T[B][m] ----
  const int mat = wave >> 1;           // 0: x, 1: xhat
  const u16* Tt = mat ? Ttxh : Ttx;
  const int ntl = wave & 1;            // n-half
  f32x4 R[2];
  R[0] = (f32x4){0,0,0,0}; R[1] = (f32x4){0,0,0,0};
  #pragma unroll
  for (int ks = 0; ks < 4; ks++){
    const int pos = (ks*4 + lq) ^ (lr & 7);
    bf16x8 af = *(const bf16x8*)&Fyb[(ntl*16 + lr)*128 + pos*8];
    #pragma unroll
    for (int mt = 0; mt < 2; mt++){
      bf16x8 bf_ = *(const bf16x8*)&Tt[(mt*16 + lr)*136 + ks*32 + lq*8];
      R[mt] = __builtin_amdgcn_mfma_f32_16x16x32_bf16(af, bf_, R[mt], 0, 0, 0);
    }
  }
  #pragma unroll
  for (int mt = 0; mt < 2; mt++){
    const int m = mt*16 + lr;
    #pragma unroll
    for (int r = 0; r < 4; r++){
      const int n = ntl*16 + lq*4 + r;
      r_bf[(size_t)b*2048 + mat*1024 + n*32 + m] = f2bf(R[mt][r]*gm);
    }
  }
}

// ---------------- bf16 B^T GEMM, split-K via blockIdx.z ----------------
struct Slice { const u16* A; const u16* W; const u16* Whi; float* C; int lda, ldw, K, pad; };
struct Slices { Slice s[4]; };

template<int BM, int BN>
__global__ __launch_bounds__(256) void gemm_bt(Slices sl, int nsplit, int ldc)
{
  constexpr int BK = 64;
  constexpr int FI = BM/32;
  constexpr int FJ = BN/32;
  __shared__ __align__(16) u16 Asm[BM*BK];
  __shared__ __align__(16) u16 Bsm[BN*BK];
  const int tid  = threadIdx.x;
  const int wave = tid >> 6;
  const int lane = tid & 63;
  const int wm = wave & 1, wn = wave >> 1;
  const int m0 = blockIdx.y * BM;
  const int n0 = blockIdx.x * BN;
  const Slice& sp = sl.s[blockIdx.z];
  const u16* Ap = sp.A;
  const u16* Wp = sp.W;
  const int lda = sp.lda, ldw = sp.ldw, K = sp.K;
  if (nsplit > 0 && n0 >= nsplit) Wp = sp.Whi - (size_t)nsplit * ldw;
  float* C = sp.C;

  f32x4 acc[FI][FJ];
  #pragma unroll
  for (int i = 0; i < FI; i++)
    #pragma unroll
    for (int j = 0; j < FJ; j++) acc[i][j] = (f32x4){0.f,0.f,0.f,0.f};

  const int lr = lane & 15;
  const int lq = lane >> 4;

  for (int kt = 0; kt < K; kt += BK){
    __syncthreads();
    constexpr int NCA = BM*BK/8;
    #pragma unroll
    for (int it = 0; it < NCA/256; it++){
      const int cb = it*256 + wave*64;
      const int c  = cb + lane;
      const int row = c >> 3;
      const int c8  = (c & 7) ^ (row & 7);
      load_lds16(Ap + (size_t)(m0 + row)*lda + kt + c8*8, &Asm[cb*8]);
    }
    constexpr int NCB = BN*BK/8;
    #pragma unroll
    for (int it = 0; it < NCB/256; it++){
      const int cb = it*256 + wave*64;
      const int c  = cb + lane;
      const int row = c >> 3;
      const int c8  = (c & 7) ^ (row & 7);
      load_lds16(Wp + (size_t)(n0 + row)*ldw + kt + c8*8, &Bsm[cb*8]);
    }
    __syncthreads();
    #pragma unroll
    for (int ks = 0; ks < 2; ks++){
      bf16x8 af[FI], bfr[FJ];
      #pragma unroll
      for (int i = 0; i < FI; i++){
        const int row = wm*(BM/2) + i*16 + lr;
        const int xx = (ks*4 + lq) ^ (row & 7);
        af[i] = *(const bf16x8*)&Asm[row*BK + xx*8];
      }
      #pragma unroll
      for (int j = 0; j < FJ; j++){
        const int row = wn*(BN/2) + j*16 + lr;
        const int xx = (ks*4 + lq) ^ (row & 7);
        bfr[j] = *(const bf16x8*)&Bsm[row*BK + xx*8];
      }
      #pragma unroll
      for (int i = 0; i < FI; i++)
        #pragma unroll
        for (int j = 0; j < FJ; j++)
          acc[i][j] = __builtin_amdgcn_mfma_f32_16x16x32_bf16(af[i], bfr[j], acc[i][j], 0, 0, 0);
    }
  }
  // C/D layout: col=lane&15, row=(lane>>4)*4+reg (m89-verified)
  #pragma unroll
  for (int i = 0; i < FI; i++){
    const int gm = m0 + wm*(BM/2) + i*16 + lq*4;
    #pragma unroll
    for (int j = 0; j < FJ; j++){
      const int gn = n0 + wn*(BN/2) + j*16 + lr;
      #pragma unroll
      for (int r = 0; r < 4; r++)
        C[(size_t)(gm + r)*ldc + gn] = acc[i][j][r];
    }
  }
}

// ---------------- LSTM pointwise (+bias +3-way partial sum +block stats) ----------------
__global__ __launch_bounds__(256) void lstm_kernel(
    const float* __restrict__ g, const float* __restrict__ bias,
    float* __restrict__ c, float* __restrict__ h, float* __restrict__ ps)
{
  const int idx = blockIdx.x*256 + threadIdx.x;  // < 262144
  const int m = idx >> 9;
  const int q = idx & 511;
  const size_t gb = (size_t)m*G4 + q*4;
  const float* g1 = g + 4194304;
  const float* g2 = g + 2*4194304;
  f32x4 gi = *(const f32x4*)&g[gb]         + *(const f32x4*)&g1[gb]         + *(const f32x4*)&g2[gb]         + *(const f32x4*)&bias[q*4];
  f32x4 gf = *(const f32x4*)&g[gb+HID]     + *(const f32x4*)&g1[gb+HID]     + *(const f32x4*)&g2[gb+HID]     + *(const f32x4*)&bias[HID+q*4];
  f32x4 gg = *(const f32x4*)&g[gb+2*HID]   + *(const f32x4*)&g1[gb+2*HID]   + *(const f32x4*)&g2[gb+2*HID]   + *(const f32x4*)&bias[2*HID+q*4];
  f32x4 go = *(const f32x4*)&g[gb+3*HID]   + *(const f32x4*)&g1[gb+3*HID]   + *(const f32x4*)&g2[gb+3*HID]   + *(const f32x4*)&bias[3*HID+q*4];
  const size_t cb = (size_t)m*HID + q*4;
  f32x4 cv = *(const f32x4*)&c[cb];
  f32x4 cn, hn;
  #pragma unroll
  for (int k = 0; k < 4; k++){
    const float ck = sigm(gf[k])*cv[k] + sigm(gi[k])*tanhf(gg[k]);
    cn[k] = ck;
    hn[k] = sigm(go[k])*tanhf(ck);
  }
  *(f32x4*)&c[cb] = cn;
  *(f32x4*)&h[cb] = hn;
  float s1 = hn[0]+hn[1]+hn[2]+hn[3];
  float s2 = hn[0]*hn[0]+hn[1]*hn[1]+hn[2]*hn[2]+hn[3]*hn[3];
  s1 = wsum(s1); s2 = wsum(s2);
  __shared__ float r1[4], r2[4];
  const int w = threadIdx.x >> 6;
  if ((threadIdx.x & 63) == 0){ r1[w] = s1; r2[w] = s2; }
  __syncthreads();
  if (threadIdx.x == 0){
    ps[blockIdx.x]        = r1[0]+r1[1]+r1[2]+r1[3];
    ps[1024 + blockIdx.x] = r2[0]+r2[1]+r2[2]+r2[3];
  }
}

// ---------------- MDL sum-exp pass ----------------
__global__ __launch_bounds__(256) void sumexp_kernel(
    const float* __restrict__ h, const float* __restrict__ ps, float* __restrict__ pe)
{
  const int tid = threadIdx.x;
  float t1 = 0.f, t2 = 0.f;
  for (int i = tid; i < 1024; i += 256){ t1 += ps[i]; t2 += ps[1024 + i]; }
  t1 = wsum(t1); t2 = wsum(t2);
  __shared__ float r1[4], r2[4];
  const int w = tid >> 6;
  if ((tid & 63) == 0){ r1[w] = t1; r2[w] = t2; }
  __syncthreads();
  __shared__ float mh[2];
  if (tid == 0){
    const float S1 = r1[0]+r1[1]+r1[2]+r1[3];
    const float S2 = r2[0]+r2[1]+r2[2]+r2[3];
    const float mean = S1*(1.f/1048576.f);
    const float var  = (S2 - 1048576.f*mean*mean)*(1.f/1048575.f);
    mh[0] = mean; mh[1] = 1.f/sqrtf(var);
  }
  __syncthreads();
  const float mean = mh[0], istd = mh[1];
  float se = 0.f;
  for (int i = blockIdx.x*256 + tid; i < (1<<18); i += 256*256){
    f32x4 v = ((const f32x4*)h)[i];
    #pragma unroll
    for (int k = 0; k < 4; k++){
      const float u = (v[k] - mean)*istd;
      se += expf(-0.5f*u*u);
    }
  }
  se = wsum(se);
  __shared__ float r3[4];
  if ((tid & 63) == 0) r3[w] = se;
  __syncthreads();
  if (tid == 0) pe[blockIdx.x] = r3[0]+r3[1]+r3[2]+r3[3];
}

// ---------------- MDL scale ----------------
__global__ __launch_bounds__(256) void scale_kernel(
    const float* __restrict__ h, const float* __restrict__ ps,
    const float* __restrict__ pe, u16* __restrict__ hb)
{
  const int tid = threadIdx.x;
  float t1 = 0.f, t2 = 0.f;
  for (int i = tid; i < 1024; i += 256){ t1 += ps[i]; t2 += ps[1024 + i]; }
  float t3 = pe[tid];
  t1 = wsum(t1); t2 = wsum(t2); t3 = wsum(t3);
  __shared__ float r1[4], r2[4], r3[4];
  const int w = tid >> 6;
  if ((tid & 63) == 0){ r1[w] = t1; r2[w] = t2; r3[w] = t3; }
  __syncthreads();
  __shared__ float lsh;
  if (tid == 0){
    const float S1 = r1[0]+r1[1]+r1[2]+r1[3];
    const float S2 = r2[0]+r2[1]+r2[2]+r2[3];
    const float SE = r3[0]+r3[1]+r3[2]+r3[3];
    const float mean = S1*(1.f/1048576.f);
    const float var  = (S2 - 1048576.f*mean*mean)*(1.f/1048575.f);
    const float stdv = sqrtf(var);
    const float lse = logf(SE) - logf(stdv) - 0.5f*LOG2PI_F;
    lsh = fmaxf(-lse, 0.f) + log1pf(expf(-fabsf(lse)));   // logaddexp(0,lse)-lse
  }
  __syncthreads();
  const float l = lsh;
  const int i = blockIdx.x*256 + tid;   // < 262144
  f32x4 v = ((const f32x4*)h)[i];
  u16x4 o;
  #pragma unroll
  for (int k = 0; k < 4; k++) o[k] = f2bf(v[k]*l);
  ((u16x4*)hb)[i] = o;
}

// ---------------- z = mu + exp(logsig)*eps (sums 4 split-K partials) ----------------
__global__ __launch_bounds__(256) void z_kernel(
    const float* __restrict__ zp, const float* __restrict__ mu_b,
    const float* __restrict__ sig_b, const float* __restrict__ ep, u16* __restrict__ zo)
{
  const int idx = blockIdx.x*256 + threadIdx.x;  // < 65536
  const int m = idx >> 7;
  const int q = idx & 127;
  const size_t base = (size_t)m*1024 + q*4;
  f32x4 mu = *(const f32x4*)&zp[base] + *(const f32x4*)&zp[524288 + base]
           + *(const f32x4*)&zp[2*524288 + base] + *(const f32x4*)&zp[3*524288 + base]
           + *(const f32x4*)&mu_b[q*4];
  f32x4 ls = *(const f32x4*)&zp[base+512] + *(const f32x4*)&zp[524288 + base+512]
           + *(const f32x4*)&zp[2*524288 + base+512] + *(const f32x4*)&zp[3*524288 + base+512]
           + *(const f32x4*)&sig_b[q*4];
  f32x4 ev = *(const f32x4*)&ep[(size_t)m*512 + q*4];
  u16x4 o;
  #pragma unroll
  for (int k = 0; k < 4; k++) o[k] = f2bf(mu[k] + expf(ls[k])*ev[k]);
  ((u16x4*)zo)[idx] = o;
}

// ---------------- fused write: attn + canvas += (Fy^T @ w @ Fx)/gamma ----------------
__global__ __launch_bounds__(256) void write_fused(
    const float* __restrict__ wp, const float* __restrict__ w_b,
    const u16* __restrict__ h_dec_bf, const float* __restrict__ attnW,
    const float* __restrict__ attn_b, float* __restrict__ canvas)
{
  const int b = blockIdx.x;
  const int tid = threadIdx.x;
  __shared__ float red[4][5];
  __shared__ float prm[5];
  __shared__ float inv[32];
  __shared__ float sW[1024];
  __shared__ __align__(16) float sF[32*132];
  __shared__ float sU[128*33];

  {
    float a0=0,a1=0,a2=0,a3=0,a4=0;
    const u16* h = h_dec_bf + (size_t)b*HID;
    for (int k = tid; k < HID; k += 256){
      const float hv = bf2f(h[k]);
      a0 += hv*attnW[k];
      a1 += hv*attnW[HID + k];
      a2 += hv*attnW[2*HID + k];
      a3 += hv*attnW[3*HID + k];
      a4 += hv*attnW[4*HID + k];
    }
    a0 = wsum(a0); a1 = wsum(a1); a2 = wsum(a2); a3 = wsum(a3); a4 = wsum(a4);
    if ((tid & 63) == 0){
      const int w = tid >> 6;
      red[w][0]=a0; red[w][1]=a1; red[w][2]=a2; red[w][3]=a3; red[w][4]=a4;
    }
  }
  for (int i = tid; i < 1024; i += 256)
    sW[i] = wp[(size_t)b*1024 + i] + wp[524288 + (size_t)b*1024 + i]
          + wp[2*524288 + (size_t)b*1024 + i] + wp[3*524288 + (size_t)b*1024 + i] + w_b[i];
  __syncthreads();
  if (tid < 5){
    const float p = red[0][tid]+red[1][tid]+red[2][tid]+red[3][tid] + attn_b[tid];
    float v;
    if (tid <= 1)      v = 64.5f*(p + 1.f);
    else if (tid == 2) v = 1.f/(2.f*expf(p));
    else if (tid == 3) v = (127.f/31.f)*expf(p);
    else               v = expf(p);
    prm[tid] = v;
  }
  __syncthreads();
  const float gx = prm[0], gy = prm[1], i2s = prm[2], dl = prm[3], gm = prm[4];

  auto genF = [&](float g0){
    for (int i = tid; i < 4096; i += 256){
      const int n = i >> 7, a = i & 127;
      const float mu = g0 + ((float)n - 16.5f)*dl;
      const float t = ((float)a - mu)*i2s;
      sF[n*132 + a] = expf(-t*t);
    }
    __syncthreads();
    if (tid < 32){
      float ssum = 0.f;
      for (int a = 0; a < 128; a++) ssum += sF[tid*132 + a];
      inv[tid] = 1.f/(ssum + 1e-9f);
    }
    __syncthreads();
    for (int i = tid; i < 4096; i += 256)
      sF[(i >> 7)*132 + (i & 127)] *= inv[i >> 7];
    __syncthreads();
  };

  genF(gy);   // Fy
  {
    const int Bg = tid & 31, mg = tid >> 5;
    float acc[4][4] = {};
    for (int n = 0; n < 32; n++){
      float fy[4], wv[4];
      #pragma unroll
      for (int i = 0; i < 4; i++) fy[i] = sF[n*132 + Bg + 32*i];
      #pragma unroll
      for (int j = 0; j < 4; j++) wv[j] = sW[n*32 + mg*4 + j];
      #pragma unroll
      for (int i = 0; i < 4; i++)
        #pragma unroll
        for (int j = 0; j < 4; j++) acc[i][j] += fy[i]*wv[j];
    }
    #pragma unroll
    for (int i = 0; i < 4; i++)
      #pragma unroll
      for (int j = 0; j < 4; j++)
        sU[(Bg + 32*i)*33 + mg*4 + j] = acc[i][j];
  }
  __syncthreads();
  genF(gx);   // Fx
  {
    const int Bg = tid & 31, ag = tid >> 5;
    float acc[64];
    #pragma unroll
    for (int k = 0; k < 64; k++) acc[k] = 0.f;
    for (int mm = 0; mm < 32; mm++){
      float u[4];
      #pragma unroll
      for (int i = 0; i < 4; i++) u[i] = sU[(Bg + 32*i)*33 + mm];
      f32x4 fx[4];
      #pragma unroll
      for (int k = 0; k < 4; k++) fx[k] = *(const f32x4*)&sF[mm*132 + ag*16 + k*4];
      #pragma unroll
      for (int i = 0; i < 4; i++)
        #pragma unroll
        for (int k = 0; k < 4; k++)
          #pragma unroll
          for (int cc = 0; cc < 4; cc++)
            acc[i*16 + k*4 + cc] += u[i]*fx[k][cc];
    }
    const float ig = 1.f/gm;
    #pragma unroll
    for (int i = 0; i < 4; i++){
      const int B_ = Bg + 32*i;
      #pragma unroll
      for (int k = 0; k < 4; k++){
        float* cp = &canvas[(size_t)b*ABF + B_*128 + ag*16 + k*4];
        f32x4 cv = *(const f32x4*)cp;
        #pragma unroll
        for (int cc = 0; cc < 4; cc++) cv[cc] += acc[i*16 + k*4 + cc]*ig;
        *(f32x4*)cp = cv;
      }
    }
  }
}

// ---------------- host ----------------
extern "C" void kernel_launch(void* const* d_in, const int* in_sizes, int n_in,
                              void* d_out, int out_size, void* d_ws, size_t ws_size,
                              hipStream_t stream)
{
  (void)in_sizes; (void)n_in; (void)out_size; (void)ws_size;
  const float* x      = (const float*)d_in[0];
  const float* eps    = (const float*)d_in[1];
  const float* encWih = (const float*)d_in[2];
  const float* encWhh = (const float*)d_in[3];
  const float* enc_b  = (const float*)d_in[4];
  const float* decWih = (const float*)d_in[5];
  const float* decWhh = (const float*)d_in[6];
  const float* dec_b  = (const float*)d_in[7];
  const float* muW    = (const float*)d_in[8];
  const float* mu_b   = (const float*)d_in[9];
  const float* sigW   = (const float*)d_in[10];
  const float* sig_b  = (const float*)d_in[11];
  const float* attnW  = (const float*)d_in[12];
  const float* attn_b = (const float*)d_in[13];
  const float* wW     = (const float*)d_in[14];
  const float* w_b    = (const float*)d_in[15];
  float* canvas = (float*)d_out;

  char* wsb = (char*)d_ws;
  size_t off = 0;
  auto alloc = [&](size_t bytes)->char*{
    char* p = wsb + off; off += (bytes + 255) & ~(size_t)255; return p;
  };
  // zeroed state region (contiguous, first)
  float* c_enc    = (float*)alloc(1048576*4);
  float* c_dec    = (float*)alloc(1048576*4);
  u16*   h_enc_bf = (u16*)  alloc(1048576*2);
  u16*   h_dec_bf = (u16*)  alloc(1048576*2);
  const size_t state_bytes = off;
  // transients
  float* ps    = (float*)alloc(2304*4);
  float* pe    = (float*)alloc(256*4);
  float* h_tmp = (float*)alloc(1048576*4);
  float* g_buf = (float*)alloc((size_t)3*4194304*4);   // 3 split-K partials
  u16*   r_bf  = (u16*)  alloc(1048576*2);
  u16*   z_bf  = (u16*)  alloc(262144*2);
  float* zbuf  = (float*)alloc((size_t)4*524288*4);
  float* wbuf  = (float*)alloc((size_t)4*524288*4);
  u16*   x_bf  = (u16*)  alloc((size_t)8388608*2);
  // bf16 weights
  u16* wih_bf  = (u16*)alloc((size_t)33554432*2);
  u16* whh_bf  = (u16*)alloc((size_t)16777216*2);
  u16* dwih_bf = (u16*)alloc((size_t)4194304*2);
  u16* dwhh_bf = (u16*)alloc((size_t)16777216*2);
  u16* muw_bf  = (u16*)alloc((size_t)1048576*2);
  u16* sigw_bf = (u16*)alloc((size_t)1048576*2);
  u16* ww_bf   = (u16*)alloc((size_t)2097152*2);

  // init
  zero_kernel<<<1024, 256, 0, stream>>>((float*)wsb, (int)(state_bytes/16));
  zero_kernel<<<2048, 256, 0, stream>>>(canvas, (ABF/4)*BSZ);
  cvt_kernel<<<2048, 256, 0, stream>>>(x,      x_bf,    8388608/4);
  cvt_kernel<<<2048, 256, 0, stream>>>(encWih, wih_bf,  33554432/4);
  cvt_kernel<<<2048, 256, 0, stream>>>(encWhh, whh_bf,  16777216/4);
  cvt_kernel<<<1024, 256, 0, stream>>>(decWih, dwih_bf, 4194304/4);
  cvt_kernel<<<2048, 256, 0, stream>>>(decWhh, dwhh_bf, 16777216/4);
  cvt_kernel<<<512,  256, 0, stream>>>(muW,    muw_bf,  1048576/4);
  cvt_kernel<<<512,  256, 0, stream>>>(sigW,   sigw_bf, 1048576/4);
  cvt_kernel<<<512,  256, 0, stream>>>(wW,     ww_bf,   2097152/4);

  float* g0 = g_buf;
  float* g1 = g_buf + 4194304;
  float* g2 = g_buf + 2*4194304;

  Slices enc_sl = {};
  enc_sl.s[0] = { r_bf,            wih_bf,          nullptr, g0, HID, 2*HID, HID, 0 };
  enc_sl.s[1] = { h_dec_bf,        wih_bf + HID,    nullptr, g1, HID, 2*HID, HID, 0 };
  enc_sl.s[2] = { h_enc_bf,        whh_bf,          nullptr, g2, HID, HID,   HID, 0 };

  Slices dec_sl = {};
  dec_sl.s[0] = { z_bf,            dwih_bf,         nullptr, g0, ZD,  ZD,    ZD,   0 };
  dec_sl.s[1] = { h_dec_bf,        dwhh_bf,         nullptr, g1, HID, HID,   1024, 0 };
  dec_sl.s[2] = { h_dec_bf + 1024, dwhh_bf + 1024,  nullptr, g2, HID, HID,   1024, 0 };

  Slices ms_sl = {}, w_sl = {};
  for (int k = 0; k < 4; k++){
    ms_sl.s[k] = { h_enc_bf + 512*k, muw_bf + 512*k, sigw_bf + 512*k, zbuf + (size_t)k*524288, HID, HID, 512, 0 };
    w_sl.s[k]  = { h_dec_bf + 512*k, ww_bf  + 512*k, nullptr,         wbuf + (size_t)k*524288, HID, HID, 512, 0 };
  }

  for (int t = 0; t < TSTEPS; t++){
    // read phase (attn from pre-update h_dec, xhat + glimpse fused, MFMA)
    read_fused<<<512, 256, 0, stream>>>(x_bf, canvas, h_dec_bf, attnW, attn_b, r_bf);
    // encoder gates, split-K 3-way
    gemm_bt<128,128><<<dim3(64,4,3), 256, 0, stream>>>(enc_sl, 0, G4);
    lstm_kernel<<<1024, 256, 0, stream>>>(g_buf, enc_b, c_enc, h_tmp, ps);
    sumexp_kernel<<<256, 256, 0, stream>>>(h_tmp, ps, pe);
    scale_kernel<<<1024, 256, 0, stream>>>(h_tmp, ps, pe, h_enc_bf);
    // mu | logsigma fused GEMM, split-K 4-way (n>=512 -> sig_W)
    gemm_bt<64,64><<<dim3(16,8,4), 256, 0, stream>>>(ms_sl, 512, 1024);
    z_kernel<<<256, 256, 0, stream>>>(zbuf, mu_b, sig_b, eps + (size_t)t*BSZ*ZD, z_bf);
    // decoder gates, split-K 3-way
    gemm_bt<128,128><<<dim3(64,4,3), 256, 0, stream>>>(dec_sl, 0, G4);
    lstm_kernel<<<1024, 256, 0, stream>>>(g_buf, dec_b, c_dec, h_tmp, ps);
    sumexp_kernel<<<256, 256, 0, stream>>>(h_tmp, ps, pe);
    scale_kernel<<<1024, 256, 0, stream>>>(h_tmp, ps, pe, h_dec_bf);
    // write phase (attn from updated h_dec)
    gemm_bt<64,64><<<dim3(16,8,4), 256, 0, stream>>>(w_sl, 0, 1024);
    write_fused<<<512, 256, 0, stream>>>(wbuf, w_b, h_dec_bf, attnW, attn_b, canvas);
  }
}

// Round 4
// 4351.307 us; speedup vs baseline: 1.6818x; 1.0441x over previous
//
#include <hip/hip_runtime.h>
#include <math.h>

#define BSZ   512
#define TSTEPS 16
#define HID   2048
#define G4    8192
#define ZD    512
#define ABF   16384
#define LOG2PI_F 1.8378770664093453f

typedef float  f32x4  __attribute__((ext_vector_type(4)));
typedef __bf16 bf16x8 __attribute__((ext_vector_type(8)));
typedef unsigned short u16;
typedef u16 u16x4 __attribute__((ext_vector_type(4)));
typedef u16 u16x8v __attribute__((ext_vector_type(8)));
union bfcast { u16x8v u; bf16x8 b; };

__device__ __forceinline__ u16 f2bf(float f){
  union { float f; unsigned u; } v; v.f = f;
  unsigned u = v.u;
  return (u16)((u + 0x7FFFu + ((u >> 16) & 1u)) >> 16);   // RNE
}
__device__ __forceinline__ float bf2f(u16 u){
  union { unsigned u; float f; } v; v.u = ((unsigned)u) << 16; return v.f;
}
__device__ __forceinline__ float sigm(float x){ return 1.f/(1.f + expf(-x)); }

__device__ __forceinline__ void load_lds16(const void* g, void* l){
  __builtin_amdgcn_global_load_lds(
      (const __attribute__((address_space(1))) void*)g,
      (__attribute__((address_space(3))) void*)l, 16, 0, 0);
}

__device__ __forceinline__ float wsum(float v){
  #pragma unroll
  for (int o = 32; o; o >>= 1) v += __shfl_down(v, o, 64);
  return v;
}

// ---------------- utility kernels ----------------
__global__ __launch_bounds__(256) void zero_kernel(float* __restrict__ p, int n4){
  int i = blockIdx.x*256 + threadIdx.x;
  const int st = gridDim.x*256;
  f32x4 z = {0.f,0.f,0.f,0.f};
  for (; i < n4; i += st) ((f32x4*)p)[i] = z;
}

__global__ __launch_bounds__(256) void cvt_kernel(const float* __restrict__ s, u16* __restrict__ d, int n4){
  int i = blockIdx.x*256 + threadIdx.x;
  const int st = gridDim.x*256;
  for (; i < n4; i += st){
    f32x4 v = ((const f32x4*)s)[i];
    u16x4 o;
    o[0]=f2bf(v[0]); o[1]=f2bf(v[1]); o[2]=f2bf(v[2]); o[3]=f2bf(v[3]);
    ((u16x4*)d)[i] = o;
  }
}

// ---------------- fused read: attn + xhat + glimpse (MFMA) ----------------
__global__ __launch_bounds__(256) void read_fused(
    const u16* __restrict__ x_bf, const float* __restrict__ canvas,
    const u16* __restrict__ h_dec_bf, const float* __restrict__ attnW,
    const float* __restrict__ attn_b, u16* __restrict__ r_bf)
{
  const int b = blockIdx.x;
  const int tid = threadIdx.x;
  const int wave = tid >> 6;
  const int lane = tid & 63;
  const int lr = lane & 15;
  const int lq = lane >> 4;
  __shared__ float red[4][5];
  __shared__ float prm[5];
  __shared__ float rowsum[32][9];
  __shared__ __align__(16) u16 Fxb[32*128];   // row n, 16B-chunk c stored at c^(n&7)
  __shared__ __align__(16) u16 Fyb[32*128];
  __shared__ __align__(16) u16 Ttx[32*136];   // T[m][B], pad to 136
  __shared__ __align__(16) u16 Ttxh[32*136];

  // ---- attn params ----
  {
    float a0=0,a1=0,a2=0,a3=0,a4=0;
    const u16* h = h_dec_bf + (size_t)b*HID;
    for (int k = tid; k < HID; k += 256){
      const float hv = bf2f(h[k]);
      a0 += hv*attnW[k];
      a1 += hv*attnW[HID + k];
      a2 += hv*attnW[2*HID + k];
      a3 += hv*attnW[3*HID + k];
      a4 += hv*attnW[4*HID + k];
    }
    a0 = wsum(a0); a1 = wsum(a1); a2 = wsum(a2); a3 = wsum(a3); a4 = wsum(a4);
    if (lane == 0){
      red[wave][0]=a0; red[wave][1]=a1; red[wave][2]=a2; red[wave][3]=a3; red[wave][4]=a4;
    }
  }
  __syncthreads();
  if (tid < 5){
    const float p = red[0][tid]+red[1][tid]+red[2][tid]+red[3][tid] + attn_b[tid];
    float v;
    if (tid <= 1)      v = 64.5f*(p + 1.f);
    else if (tid == 2) v = 1.f/(2.f*expf(p));       // i2s
    else if (tid == 3) v = (127.f/31.f)*expf(p);    // delta
    else               v = expf(p);                  // gamma
    prm[tid] = v;
  }
  __syncthreads();
  const float gx = prm[0], gy = prm[1], i2s = prm[2], dl = prm[3], gm = prm[4];

  // ---- F generation (bf16, swizzled) ----
  auto genF = [&](float g0, u16* dst){
    const int rr = tid >> 3;
    const int asub = tid & 7;
    const float mu = g0 + ((float)rr - 16.5f)*dl;
    float s = 0.f;
    for (int a = asub*16; a < asub*16 + 16; a++){
      const float t = ((float)a - mu)*i2s;
      s += expf(-t*t);
    }
    rowsum[rr][asub] = s;
    __syncthreads();
    if (tid < 32){
      float tot = 0.f;
      #pragma unroll
      for (int j = 0; j < 8; j++) tot += rowsum[tid][j];
      rowsum[tid][8] = 1.f/(tot + 1e-9f);
    }
    __syncthreads();
    for (int i = tid; i < 4096; i += 256){
      const int n = i >> 7, a = i & 127;
      const float mu2 = g0 + ((float)n - 16.5f)*dl;
      const float t = ((float)a - mu2)*i2s;
      const float v = expf(-t*t)*rowsum[n][8];
      const int pos = (a >> 3) ^ (n & 7);
      dst[n*128 + pos*8 + (a & 7)] = f2bf(v);
    }
    __syncthreads();
  };
  genF(gx, Fxb);
  genF(gy, Fyb);

  // ---- stage 1: T[B][m] = sum_a img[B][a] Fx[m][a], per wave: B-rows [32w,32w+32) ----
  const u16*   xb = x_bf   + (size_t)b*ABF;
  const float* cb = canvas + (size_t)b*ABF;
  f32x4 Cx[2][2], Ch[2][2];
  #pragma unroll
  for (int i = 0; i < 2; i++)
    #pragma unroll
    for (int j = 0; j < 2; j++){ Cx[i][j] = (f32x4){0,0,0,0}; Ch[i][j] = (f32x4){0,0,0,0}; }

  #pragma unroll
  for (int mt = 0; mt < 2; mt++){
    const int row = wave*32 + mt*16 + lr;
    bfcast ax[4], ah[4];
    #pragma unroll
    for (int ks = 0; ks < 4; ks++){
      const int base = row*128 + ks*32 + lq*8;
      ax[ks].u = *(const u16x8v*)&xb[base];
      f32x4 c0 = *(const f32x4*)&cb[base];
      f32x4 c1 = *(const f32x4*)&cb[base + 4];
      #pragma unroll
      for (int j = 0; j < 4; j++){
        ah[ks].u[j]   = f2bf(bf2f(ax[ks].u[j])   - sigm(c0[j]));
        ah[ks].u[4+j] = f2bf(bf2f(ax[ks].u[4+j]) - sigm(c1[j]));
      }
    }
    #pragma unroll
    for (int nt = 0; nt < 2; nt++){
      #pragma unroll
      for (int ks = 0; ks < 4; ks++){
        const int pos = (ks*4 + lq) ^ (lr & 7);
        bf16x8 bf_ = *(const bf16x8*)&Fxb[(nt*16 + lr)*128 + pos*8];
        Cx[mt][nt] = __builtin_amdgcn_mfma_f32_16x16x32_bf16(ax[ks].b, bf_, Cx[mt][nt], 0, 0, 0);
        Ch[mt][nt] = __builtin_amdgcn_mfma_f32_16x16x32_bf16(ah[ks].b, bf_, Ch[mt][nt], 0, 0, 0);
      }
    }
  }
  // write T to LDS as bf16 [m][B] (C-layout: col=lane&15 -> m, row=lq*4+r -> B)
  #pragma unroll
  for (int mt = 0; mt < 2; mt++)
    #pragma unroll
    for (int nt = 0; nt < 2; nt++)
      #pragma unroll
      for (int r = 0; r < 4; r++){
        const int m  = nt*16 + lr;
        const int B_ = wave*32 + mt*16 + lq*4 + r;
        Ttx[m*136 + B_]  = f2bf(Cx[mt][nt][r]);
        Ttxh[m*136 + B_] = f2bf(Ch[mt][nt][r]);
      }
  __syncthreads();

  // ---- stage 2: r[n][m] = sum_B Fy[n][B] T[B][m] ----
  const int mat = wave >> 1;           // 0: x, 1: xhat
  const u16* Tt = mat ? Ttxh : Ttx;
  const int ntl = wave & 1;            // n-half
  f32x4 R[2];
  R[0] = (f32x4){0,0,0,0}; R[1] = (f32x4){0,0,0,0};
  #pragma unroll
  for (int ks = 0; ks < 4; ks++){
    const int pos = (ks*4 + lq) ^ (lr & 7);
    bf16x8 af = *(const bf16x8*)&Fyb[(ntl*16 + lr)*128 + pos*8];
    #pragma unroll
    for (int mt = 0; mt < 2; mt++){
      bf16x8 bf_ = *(const bf16x8*)&Tt[(mt*16 + lr)*136 + ks*32 + lq*8];
      R[mt] = __builtin_amdgcn_mfma_f32_16x16x32_bf16(af, bf_, R[mt], 0, 0, 0);
    }
  }
  #pragma unroll
  for (int mt = 0; mt < 2; mt++){
    const int m = mt*16 + lr;
    #pragma unroll
    for (int r = 0; r < 4; r++){
      const int n = ntl*16 + lq*4 + r;
      r_bf[(size_t)b*2048 + mat*1024 + n*32 + m] = f2bf(R[mt][r]*gm);
    }
  }
}

// ---------------- bf16 B^T GEMM, split-K via blockIdx.z ----------------
struct Slice { const u16* A; const u16* W; const u16* Whi; float* C; int lda, ldw, K, pad; };
struct Slices { Slice s[4]; };

template<int BM, int BN>
__global__ __launch_bounds__(256) void gemm_bt(Slices sl, int nsplit, int ldc)
{
  constexpr int BK = 64;
  constexpr int FI = BM/32;
  constexpr int FJ = BN/32;
  __shared__ __align__(16) u16 Asm[BM*BK];
  __shared__ __align__(16) u16 Bsm[BN*BK];
  const int tid  = threadIdx.x;
  const int wave = tid >> 6;
  const int lane = tid & 63;
  const int wm = wave & 1, wn = wave >> 1;
  const int m0 = blockIdx.y * BM;
  const int n0 = blockIdx.x * BN;
  const Slice& sp = sl.s[blockIdx.z];
  const u16* Ap = sp.A;
  const u16* Wp = sp.W;
  const int lda = sp.lda, ldw = sp.ldw, K = sp.K;
  if (nsplit > 0 && n0 >= nsplit) Wp = sp.Whi - (size_t)nsplit * ldw;
  float* C = sp.C;

  f32x4 acc[FI][FJ];
  #pragma unroll
  for (int i = 0; i < FI; i++)
    #pragma unroll
    for (int j = 0; j < FJ; j++) acc[i][j] = (f32x4){0.f,0.f,0.f,0.f};

  const int lr = lane & 15;
  const int lq = lane >> 4;

  for (int kt = 0; kt < K; kt += BK){
    __syncthreads();
    constexpr int NCA = BM*BK/8;
    #pragma unroll
    for (int it = 0; it < NCA/256; it++){
      const int cb = it*256 + wave*64;
      const int c  = cb + lane;
      const int row = c >> 3;
      const int c8  = (c & 7) ^ (row & 7);
      load_lds16(Ap + (size_t)(m0 + row)*lda + kt + c8*8, &Asm[cb*8]);
    }
    constexpr int NCB = BN*BK/8;
    #pragma unroll
    for (int it = 0; it < NCB/256; it++){
      const int cb = it*256 + wave*64;
      const int c  = cb + lane;
      const int row = c >> 3;
      const int c8  = (c & 7) ^ (row & 7);
      load_lds16(Wp + (size_t)(n0 + row)*ldw + kt + c8*8, &Bsm[cb*8]);
    }
    __syncthreads();
    #pragma unroll
    for (int ks = 0; ks < 2; ks++){
      bf16x8 af[FI], bfr[FJ];
      #pragma unroll
      for (int i = 0; i < FI; i++){
        const int row = wm*(BM/2) + i*16 + lr;
        const int xx = (ks*4 + lq) ^ (row & 7);
        af[i] = *(const bf16x8*)&Asm[row*BK + xx*8];
      }
      #pragma unroll
      for (int j = 0; j < FJ; j++){
        const int row = wn*(BN/2) + j*16 + lr;
        const int xx = (ks*4 + lq) ^ (row & 7);
        bfr[j] = *(const bf16x8*)&Bsm[row*BK + xx*8];
      }
      #pragma unroll
      for (int i = 0; i < FI; i++)
        #pragma unroll
        for (int j = 0; j < FJ; j++)
          acc[i][j] = __builtin_amdgcn_mfma_f32_16x16x32_bf16(af[i], bfr[j], acc[i][j], 0, 0, 0);
    }
  }
  // C/D layout: col=lane&15, row=(lane>>4)*4+reg (m89-verified)
  #pragma unroll
  for (int i = 0; i < FI; i++){
    const int gm = m0 + wm*(BM/2) + i*16 + lq*4;
    #pragma unroll
    for (int j = 0; j < FJ; j++){
      const int gn = n0 + wn*(BN/2) + j*16 + lr;
      #pragma unroll
      for (int r = 0; r < 4; r++)
        C[(size_t)(gm + r)*ldc + gn] = acc[i][j][r];
    }
  }
}

// ---------------- LSTM pointwise (+bias +3-way partial sum +block stats) ----------------
__global__ __launch_bounds__(256) void lstm_kernel(
    const float* __restrict__ g, const float* __restrict__ bias,
    float* __restrict__ c, float* __restrict__ h, float* __restrict__ ps)
{
  const int idx = blockIdx.x*256 + threadIdx.x;  // < 262144
  const int m = idx >> 9;
  const int q = idx & 511;
  const size_t gb = (size_t)m*G4 + q*4;
  const float* g1 = g + 4194304;
  const float* g2 = g + 2*4194304;
  f32x4 gi = *(const f32x4*)&g[gb]         + *(const f32x4*)&g1[gb]         + *(const f32x4*)&g2[gb]         + *(const f32x4*)&bias[q*4];
  f32x4 gf = *(const f32x4*)&g[gb+HID]     + *(const f32x4*)&g1[gb+HID]     + *(const f32x4*)&g2[gb+HID]     + *(const f32x4*)&bias[HID+q*4];
  f32x4 gg = *(const f32x4*)&g[gb+2*HID]   + *(const f32x4*)&g1[gb+2*HID]   + *(const f32x4*)&g2[gb+2*HID]   + *(const f32x4*)&bias[2*HID+q*4];
  f32x4 go = *(const f32x4*)&g[gb+3*HID]   + *(const f32x4*)&g1[gb+3*HID]   + *(const f32x4*)&g2[gb+3*HID]   + *(const f32x4*)&bias[3*HID+q*4];
  const size_t cb = (size_t)m*HID + q*4;
  f32x4 cv = *(const f32x4*)&c[cb];
  f32x4 cn, hn;
  #pragma unroll
  for (int k = 0; k < 4; k++){
    const float ck = sigm(gf[k])*cv[k] + sigm(gi[k])*tanhf(gg[k]);
    cn[k] = ck;
    hn[k] = sigm(go[k])*tanhf(ck);
  }
  *(f32x4*)&c[cb] = cn;
  *(f32x4*)&h[cb] = hn;
  float s1 = hn[0]+hn[1]+hn[2]+hn[3];
  float s2 = hn[0]*hn[0]+hn[1]*hn[1]+hn[2]*hn[2]+hn[3]*hn[3];
  s1 = wsum(s1); s2 = wsum(s2);
  __shared__ float r1[4], r2[4];
  const int w = threadIdx.x >> 6;
  if ((threadIdx.x & 63) == 0){ r1[w] = s1; r2[w] = s2; }
  __syncthreads();
  if (threadIdx.x == 0){
    ps[blockIdx.x]        = r1[0]+r1[1]+r1[2]+r1[3];
    ps[1024 + blockIdx.x] = r2[0]+r2[1]+r2[2]+r2[3];
  }
}

// ---------------- MDL sum-exp pass ----------------
__global__ __launch_bounds__(256) void sumexp_kernel(
    const float* __restrict__ h, const float* __restrict__ ps, float* __restrict__ pe)
{
  const int tid = threadIdx.x;
  float t1 = 0.f, t2 = 0.f;
  for (int i = tid; i < 1024; i += 256){ t1 += ps[i]; t2 += ps[1024 + i]; }
  t1 = wsum(t1); t2 = wsum(t2);
  __shared__ float r1[4], r2[4];
  const int w = tid >> 6;
  if ((tid & 63) == 0){ r1[w] = t1; r2[w] = t2; }
  __syncthreads();
  __shared__ float mh[2];
  if (tid == 0){
    const float S1 = r1[0]+r1[1]+r1[2]+r1[3];
    const float S2 = r2[0]+r2[1]+r2[2]+r2[3];
    const float mean = S1*(1.f/1048576.f);
    const float var  = (S2 - 1048576.f*mean*mean)*(1.f/1048575.f);
    mh[0] = mean; mh[1] = 1.f/sqrtf(var);
  }
  __syncthreads();
  const float mean = mh[0], istd = mh[1];
  float se = 0.f;
  for (int i = blockIdx.x*256 + tid; i < (1<<18); i += 256*256){
    f32x4 v = ((const f32x4*)h)[i];
    #pragma unroll
    for (int k = 0; k < 4; k++){
      const float u = (v[k] - mean)*istd;
      se += expf(-0.5f*u*u);
    }
  }
  se = wsum(se);
  __shared__ float r3[4];
  if ((tid & 63) == 0) r3[w] = se;
  __syncthreads();
  if (tid == 0) pe[blockIdx.x] = r3[0]+r3[1]+r3[2]+r3[3];
}

// ---------------- MDL scale ----------------
__global__ __launch_bounds__(256) void scale_kernel(
    const float* __restrict__ h, const float* __restrict__ ps,
    const float* __restrict__ pe, u16* __restrict__ hb)
{
  const int tid = threadIdx.x;
  float t1 = 0.f, t2 = 0.f;
  for (int i = tid; i < 1024; i += 256){ t1 += ps[i]; t2 += ps[1024 + i]; }
  float t3 = pe[tid];
  t1 = wsum(t1); t2 = wsum(t2); t3 = wsum(t3);
  __shared__ float r1[4], r2[4], r3[4];
  const int w = tid >> 6;
  if ((tid & 63) == 0){ r1[w] = t1; r2[w] = t2; r3[w] = t3; }
  __syncthreads();
  __shared__ float lsh;
  if (tid == 0){
    const float S1 = r1[0]+r1[1]+r1[2]+r1[3];
    const float S2 = r2[0]+r2[1]+r2[2]+r2[3];
    const float SE = r3[0]+r3[1]+r3[2]+r3[3];
    const float mean = S1*(1.f/1048576.f);
    const float var  = (S2 - 1048576.f*mean*mean)*(1.f/1048575.f);
    const float stdv = sqrtf(var);
    const float lse = logf(SE) - logf(stdv) - 0.5f*LOG2PI_F;
    lsh = fmaxf(-lse, 0.f) + log1pf(expf(-fabsf(lse)));   // logaddexp(0,lse)-lse
  }
  __syncthreads();
  const float l = lsh;
  const int i = blockIdx.x*256 + tid;   // < 262144
  f32x4 v = ((const f32x4*)h)[i];
  u16x4 o;
  #pragma unroll
  for (int k = 0; k < 4; k++) o[k] = f2bf(v[k]*l);
  ((u16x4*)hb)[i] = o;
}

// ---------------- z = mu + exp(logsig)*eps (sums 4 split-K partials) ----------------
__global__ __launch_bounds__(256) void z_kernel(
    const float* __restrict__ zp, const float* __restrict__ mu_b,
    const float* __restrict__ sig_b, const float* __restrict__ ep, u16* __restrict__ zo)
{
  const int idx = blockIdx.x*256 + threadIdx.x;  // < 65536
  const int m = idx >> 7;
  const int q = idx & 127;
  const size_t base = (size_t)m*1024 + q*4;
  f32x4 mu = *(const f32x4*)&zp[base] + *(const f32x4*)&zp[524288 + base]
           + *(const f32x4*)&zp[2*524288 + base] + *(const f32x4*)&zp[3*524288 + base]
           + *(const f32x4*)&mu_b[q*4];
  f32x4 ls = *(const f32x4*)&zp[base+512] + *(const f32x4*)&zp[524288 + base+512]
           + *(const f32x4*)&zp[2*524288 + base+512] + *(const f32x4*)&zp[3*524288 + base+512]
           + *(const f32x4*)&sig_b[q*4];
  f32x4 ev = *(const f32x4*)&ep[(size_t)m*512 + q*4];
  u16x4 o;
  #pragma unroll
  for (int k = 0; k < 4; k++) o[k] = f2bf(mu[k] + expf(ls[k])*ev[k]);
  ((u16x4*)zo)[idx] = o;
}

// ---------------- fused write: attn + canvas += (Fy^T @ w @ Fx)/gamma ----------------
__global__ __launch_bounds__(256) void write_fused(
    const float* __restrict__ wp, const float* __restrict__ w_b,
    const u16* __restrict__ h_dec_bf, const float* __restrict__ attnW,
    const float* __restrict__ attn_b, float* __restrict__ canvas)
{
  const int b = blockIdx.x;
  const int tid = threadIdx.x;
  __shared__ float red[4][5];
  __shared__ float prm[5];
  __shared__ float inv[32];
  __shared__ float sW[1024];
  __shared__ __align__(16) float sF[32*132];
  __shared__ float sU[128*33];

  {
    float a0=0,a1=0,a2=0,a3=0,a4=0;
    const u16* h = h_dec_bf + (size_t)b*HID;
    for (int k = tid; k < HID; k += 256){
      const float hv = bf2f(h[k]);
      a0 += hv*attnW[k];
      a1 += hv*attnW[HID + k];
      a2 += hv*attnW[2*HID + k];
      a3 += hv*attnW[3*HID + k];
      a4 += hv*attnW[4*HID + k];
    }
    a0 = wsum(a0); a1 = wsum(a1); a2 = wsum(a2); a3 = wsum(a3); a4 = wsum(a4);
    if ((tid & 63) == 0){
      const int w = tid >> 6;
      red[w][0]=a0; red[w][1]=a1; red[w][2]=a2; red[w][3]=a3; red[w][4]=a4;
    }
  }
  for (int i = tid; i < 1024; i += 256)
    sW[i] = wp[(size_t)b*1024 + i] + wp[524288 + (size_t)b*1024 + i]
          + wp[2*524288 + (size_t)b*1024 + i] + wp[3*524288 + (size_t)b*1024 + i] + w_b[i];
  __syncthreads();
  if (tid < 5){
    const float p = red[0][tid]+red[1][tid]+red[2][tid]+red[3][tid] + attn_b[tid];
    float v;
    if (tid <= 1)      v = 64.5f*(p + 1.f);
    else if (tid == 2) v = 1.f/(2.f*expf(p));
    else if (tid == 3) v = (127.f/31.f)*expf(p);
    else               v = expf(p);
    prm[tid] = v;
  }
  __syncthreads();
  const float gx = prm[0], gy = prm[1], i2s = prm[2], dl = prm[3], gm = prm[4];

  auto genF = [&](float g0){
    for (int i = tid; i < 4096; i += 256){
      const int n = i >> 7, a = i & 127;
      const float mu = g0 + ((float)n - 16.5f)*dl;
      const float t = ((float)a - mu)*i2s;
      sF[n*132 + a] = expf(-t*t);
    }
    __syncthreads();
    if (tid < 32){
      float ssum = 0.f;
      for (int a = 0; a < 128; a++) ssum += sF[tid*132 + a];
      inv[tid] = 1.f/(ssum + 1e-9f);
    }
    __syncthreads();
    for (int i = tid; i < 4096; i += 256)
      sF[(i >> 7)*132 + (i & 127)] *= inv[i >> 7];
    __syncthreads();
  };

  genF(gy);   // Fy
  {
    const int Bg = tid & 31, mg = tid >> 5;
    float acc[4][4] = {};
    for (int n = 0; n < 32; n++){
      float fy[4], wv[4];
      #pragma unroll
      for (int i = 0; i < 4; i++) fy[i] = sF[n*132 + Bg + 32*i];
      #pragma unroll
      for (int j = 0; j < 4; j++) wv[j] = sW[n*32 + mg*4 + j];
      #pragma unroll
      for (int i = 0; i < 4; i++)
        #pragma unroll
        for (int j = 0; j < 4; j++) acc[i][j] += fy[i]*wv[j];
    }
    #pragma unroll
    for (int i = 0; i < 4; i++)
      #pragma unroll
      for (int j = 0; j < 4; j++)
        sU[(Bg + 32*i)*33 + mg*4 + j] = acc[i][j];
  }
  __syncthreads();
  genF(gx);   // Fx
  {
    const int Bg = tid & 31, ag = tid >> 5;
    float acc[64];
    #pragma unroll
    for (int k = 0; k < 64; k++) acc[k] = 0.f;
    for (int mm = 0; mm < 32; mm++){
      float u[4];
      #pragma unroll
      for (int i = 0; i < 4; i++) u[i] = sU[(Bg + 32*i)*33 + mm];
      f32x4 fx[4];
      #pragma unroll
      for (int k = 0; k < 4; k++) fx[k] = *(const f32x4*)&sF[mm*132 + ag*16 + k*4];
      #pragma unroll
      for (int i = 0; i < 4; i++)
        #pragma unroll
        for (int k = 0; k < 4; k++)
          #pragma unroll
          for (int cc = 0; cc < 4; cc++)
            acc[i*16 + k*4 + cc] += u[i]*fx[k][cc];
    }
    const float ig = 1.f/gm;
    #pragma unroll
    for (int i = 0; i < 4; i++){
      const int B_ = Bg + 32*i;
      #pragma unroll
      for (int k = 0; k < 4; k++){
        float* cp = &canvas[(size_t)b*ABF + B_*128 + ag*16 + k*4];
        f32x4 cv = *(const f32x4*)cp;
        #pragma unroll
        for (int cc = 0; cc < 4; cc++) cv[cc] += acc[i*16 + k*4 + cc]*ig;
        *(f32x4*)cp = cv;
      }
    }
  }
}

// ---------------- host ----------------
extern "C" void kernel_launch(void* const* d_in, const int* in_sizes, int n_in,
                              void* d_out, int out_size, void* d_ws, size_t ws_size,
                              hipStream_t stream)
{
  (void)in_sizes; (void)n_in; (void)out_size; (void)ws_size;
  const float* x      = (const float*)d_in[0];
  const float* eps    = (const float*)d_in[1];
  const float* encWih = (const float*)d_in[2];
  const float* encWhh = (const float*)d_in[3];
  const float* enc_b  = (const float*)d_in[4];
  const float* decWih = (const float*)d_in[5];
  const float* decWhh = (const float*)d_in[6];
  const float* dec_b  = (const float*)d_in[7];
  const float* muW    = (const float*)d_in[8];
  const float* mu_b   = (const float*)d_in[9];
  const float* sigW   = (const float*)d_in[10];
  const float* sig_b  = (const float*)d_in[11];
  const float* attnW  = (const float*)d_in[12];
  const float* attn_b = (const float*)d_in[13];
  const float* wW     = (const float*)d_in[14];
  const float* w_b    = (const float*)d_in[15];
  float* canvas = (float*)d_out;

  char* wsb = (char*)d_ws;
  size_t off = 0;
  auto alloc = [&](size_t bytes)->char*{
    char* p = wsb + off; off += (bytes + 255) & ~(size_t)255; return p;
  };
  // zeroed state region (contiguous, first)
  float* c_enc    = (float*)alloc(1048576*4);
  float* c_dec    = (float*)alloc(1048576*4);
  u16*   h_enc_bf = (u16*)  alloc(1048576*2);
  u16*   h_dec_bf = (u16*)  alloc(1048576*2);
  const size_t state_bytes = off;
  // transients
  float* ps    = (float*)alloc(2304*4);
  float* pe    = (float*)alloc(256*4);
  float* h_tmp = (float*)alloc(1048576*4);
  float* g_buf = (float*)alloc((size_t)3*4194304*4);   // 3 split-K partials
  u16*   r_bf  = (u16*)  alloc(1048576*2);
  u16*   z_bf  = (u16*)  alloc(262144*2);
  float* zbuf  = (float*)alloc((size_t)4*524288*4);
  float* wbuf  = (float*)alloc((size_t)4*524288*4);
  u16*   x_bf  = (u16*)  alloc((size_t)8388608*2);
  // bf16 weights
  u16* wih_bf  = (u16*)alloc((size_t)33554432*2);
  u16* whh_bf  = (u16*)alloc((size_t)16777216*2);
  u16* dwih_bf = (u16*)alloc((size_t)4194304*2);
  u16* dwhh_bf = (u16*)alloc((size_t)16777216*2);
  u16* muw_bf  = (u16*)alloc((size_t)1048576*2);
  u16* sigw_bf = (u16*)alloc((size_t)1048576*2);
  u16* ww_bf   = (u16*)alloc((size_t)2097152*2);

  // init
  zero_kernel<<<1024, 256, 0, stream>>>((float*)wsb, (int)(state_bytes/16));
  zero_kernel<<<2048, 256, 0, stream>>>(canvas, (ABF/4)*BSZ);
  cvt_kernel<<<2048, 256, 0, stream>>>(x,      x_bf,    8388608/4);
  cvt_kernel<<<2048, 256, 0, stream>>>(encWih, wih_bf,  33554432/4);
  cvt_kernel<<<2048, 256, 0, stream>>>(encWhh, whh_bf,  16777216/4);
  cvt_kernel<<<1024, 256, 0, stream>>>(decWih, dwih_bf, 4194304/4);
  cvt_kernel<<<2048, 256, 0, stream>>>(decWhh, dwhh_bf, 16777216/4);
  cvt_kernel<<<512,  256, 0, stream>>>(muW,    muw_bf,  1048576/4);
  cvt_kernel<<<512,  256, 0, stream>>>(sigW,   sigw_bf, 1048576/4);
  cvt_kernel<<<512,  256, 0, stream>>>(wW,     ww_bf,   2097152/4);

  float* g0 = g_buf;
  float* g1 = g_buf + 4194304;
  float* g2 = g_buf + 2*4194304;

  Slices enc_sl = {};
  enc_sl.s[0] = { r_bf,            wih_bf,          nullptr, g0, HID, 2*HID, HID, 0 };
  enc_sl.s[1] = { h_dec_bf,        wih_bf + HID,    nullptr, g1, HID, 2*HID, HID, 0 };
  enc_sl.s[2] = { h_enc_bf,        whh_bf,          nullptr, g2, HID, HID,   HID, 0 };

  Slices dec_sl = {};
  dec_sl.s[0] = { z_bf,            dwih_bf,         nullptr, g0, ZD,  ZD,    ZD,   0 };
  dec_sl.s[1] = { h_dec_bf,        dwhh_bf,         nullptr, g1, HID, HID,   1024, 0 };
  dec_sl.s[2] = { h_dec_bf + 1024, dwhh_bf + 1024,  nullptr, g2, HID, HID,   1024, 0 };

  Slices ms_sl = {}, w_sl = {};
  for (int k = 0; k < 4; k++){
    ms_sl.s[k] = { h_enc_bf + 512*k, muw_bf + 512*k, sigw_bf + 512*k, zbuf + (size_t)k*524288, HID, HID, 512, 0 };
    w_sl.s[k]  = { h_dec_bf + 512*k, ww_bf  + 512*k, nullptr,         wbuf + (size_t)k*524288, HID, HID, 512, 0 };
  }

  for (int t = 0; t < TSTEPS; t++){
    // read phase (attn from pre-update h_dec, xhat + glimpse fused, MFMA)
    read_fused<<<512, 256, 0, stream>>>(x_bf, canvas, h_dec_bf, attnW, attn_b, r_bf);
    // encoder gates, split-K 3-way, 64x128 tile for 6 blocks/CU
    gemm_bt<64,128><<<dim3(64,8,3), 256, 0, stream>>>(enc_sl, 0, G4);
    lstm_kernel<<<1024, 256, 0, stream>>>(g_buf, enc_b, c_enc, h_tmp, ps);
    sumexp_kernel<<<256, 256, 0, stream>>>(h_tmp, ps, pe);
    scale_kernel<<<1024, 256, 0, stream>>>(h_tmp, ps, pe, h_enc_bf);
    // mu | logsigma fused GEMM, split-K 4-way (n>=512 -> sig_W)
    gemm_bt<64,64><<<dim3(16,8,4), 256, 0, stream>>>(ms_sl, 512, 1024);
    z_kernel<<<256, 256, 0, stream>>>(zbuf, mu_b, sig_b, eps + (size_t)t*BSZ*ZD, z_bf);
    // decoder gates, split-K 3-way
    gemm_bt<64,128><<<dim3(64,8,3), 256, 0, stream>>>(dec_sl, 0, G4);
    lstm_kernel<<<1024, 256, 0, stream>>>(g_buf, dec_b, c_dec, h_tmp, ps);
    sumexp_kernel<<<256, 256, 0, stream>>>(h_tmp, ps, pe);
    scale_kernel<<<1024, 256, 0, stream>>>(h_tmp, ps, pe, h_dec_bf);
    // write phase (attn from updated h_dec)
    gemm_bt<64,64><<<dim3(16,8,4), 256, 0, stream>>>(w_sl, 0, 1024);
    write_fused<<<512, 256, 0, stream>>>(wbuf, w_b, h_dec_bf, attnW, attn_b, canvas);
  }
}